// Round 1
// baseline (294.095 us; speedup 1.0000x reference)
//
#include <hip/hip_runtime.h>
#include <hip/hip_bf16.h>

typedef __attribute__((ext_vector_type(8))) short bf16x8;   // 8 bf16 (4 VGPRs)
typedef __attribute__((ext_vector_type(4))) float f32x4;    // MFMA C/D

#define KTOT 9216   // 1024 (gelu part) + 1024*8 (spline bases part)
#define NB   8192
#define NIN  1024
#define NOUT 1024

__device__ __forceinline__ void load_lds16(const void* g, void* l) {
  __builtin_amdgcn_global_load_lds(
      (const __attribute__((address_space(1))) void*)g,
      (__attribute__((address_space(3))) void*)l, 16, 0, 0);
}

// ---------------------------------------------------------------------------
// Kernel 1: A[b, 0:1024] = gelu(x[b,i]) ; A[b, 1024 + i*8 + k] = bspline basis
// grid is uniform & identical across rows -> read 12 knots, hoist reciprocals,
// amortize over 8 batch rows per thread.
// ---------------------------------------------------------------------------
__global__ void build_A(const float* __restrict__ x,
                        const float* __restrict__ grid,
                        __hip_bfloat16* __restrict__ A) {
  const int tid = blockIdx.x * blockDim.x + threadIdx.x;   // 0 .. 1048575
  const int i  = tid & (NIN - 1);
  const int b0 = (tid >> 10) << 3;                         // 8 rows / thread

  float g[12];
#pragma unroll
  for (int j = 0; j < 12; ++j) g[j] = grid[j];

  float invdr1[10], invdd1[10], invdr2[9], invdd2[9], invdr3[8], invdd3[8];
#pragma unroll
  for (int j = 0; j < 10; ++j) {
    invdr1[j] = __builtin_amdgcn_rcpf(g[j + 1] - g[j]);
    invdd1[j] = __builtin_amdgcn_rcpf(g[j + 2] - g[j + 1]);
  }
#pragma unroll
  for (int j = 0; j < 9; ++j) {
    invdr2[j] = __builtin_amdgcn_rcpf(g[j + 2] - g[j]);
    invdd2[j] = __builtin_amdgcn_rcpf(g[j + 3] - g[j + 1]);
  }
#pragma unroll
  for (int j = 0; j < 8; ++j) {
    invdr3[j] = __builtin_amdgcn_rcpf(g[j + 3] - g[j]);
    invdd3[j] = __builtin_amdgcn_rcpf(g[j + 4] - g[j + 1]);
  }

  for (int bb = 0; bb < 8; ++bb) {
    const int b = b0 + bb;
    const float xv = x[(size_t)b * NIN + i];
    const float ge = 0.5f * xv * (1.0f + erff(xv * 0.70710678118654752f));
    __hip_bfloat16* Arow = A + (size_t)b * KTOT;
    Arow[i] = __float2bfloat16(ge);

    float bas[11];
#pragma unroll
    for (int j = 0; j < 11; ++j)
      bas[j] = (xv >= g[j] && xv < g[j + 1]) ? 1.0f : 0.0f;
#pragma unroll
    for (int j = 0; j < 10; ++j)   // k = 1
      bas[j] = (xv - g[j]) * invdr1[j] * bas[j] + (g[j + 2] - xv) * invdd1[j] * bas[j + 1];
#pragma unroll
    for (int j = 0; j < 9; ++j)    // k = 2
      bas[j] = (xv - g[j]) * invdr2[j] * bas[j] + (g[j + 3] - xv) * invdd2[j] * bas[j + 1];
#pragma unroll
    for (int j = 0; j < 8; ++j)    // k = 3
      bas[j] = (xv - g[j]) * invdr3[j] * bas[j] + (g[j + 4] - xv) * invdd3[j] * bas[j + 1];

    union { __hip_bfloat16 h[8]; uint4 v; } u;
#pragma unroll
    for (int k = 0; k < 8; ++k) u.h[k] = __float2bfloat16(bas[k]);
    *reinterpret_cast<uint4*>(Arow + NIN + i * 8) = u.v;   // 16B coalesced store
  }
}

// ---------------------------------------------------------------------------
// Kernel 2: W[o, 0:1024] = base_weight[o,:] ; W[o, 1024:] = spline_weight[o,:,:]
// ---------------------------------------------------------------------------
__global__ void convert_W(const float* __restrict__ bw,
                          const float* __restrict__ sw,
                          __hip_bfloat16* __restrict__ W) {
  const int idx = blockIdx.x * blockDim.x + threadIdx.x;   // 0 .. 1179647
  const int o  = idx / 1152;                               // 9216/8 chunks per row
  const int c8 = (idx - o * 1152) * 8;
  const float* src = (c8 < 1024) ? (bw + (size_t)o * 1024 + c8)
                                 : (sw + (size_t)o * 8192 + (c8 - 1024));
  float4 f0 = reinterpret_cast<const float4*>(src)[0];
  float4 f1 = reinterpret_cast<const float4*>(src)[1];
  union { __hip_bfloat16 h[8]; uint4 v; } u;
  u.h[0] = __float2bfloat16(f0.x); u.h[1] = __float2bfloat16(f0.y);
  u.h[2] = __float2bfloat16(f0.z); u.h[3] = __float2bfloat16(f0.w);
  u.h[4] = __float2bfloat16(f1.x); u.h[5] = __float2bfloat16(f1.y);
  u.h[6] = __float2bfloat16(f1.z); u.h[7] = __float2bfloat16(f1.w);
  *reinterpret_cast<uint4*>(W + (size_t)o * KTOT + c8) = u.v;
}

// ---------------------------------------------------------------------------
// Kernel 3: C[m,n] = sum_k A[m,k] * W[n,k]   (both K-major, bf16, fp32 out)
// m97 structure: 128x128 tile, BK=32, 4 waves, global_load_lds width=16,
// 16 x mfma_f32_16x16x32_bf16 + 8 x ds_read_b128 per K-step.
// ---------------------------------------------------------------------------
__global__ void gemm_bt(const __hip_bfloat16* __restrict__ A,
                        const __hip_bfloat16* __restrict__ Bw,
                        float* __restrict__ C) {
  __shared__ __hip_bfloat16 As[128 * 32];
  __shared__ __hip_bfloat16 Bs[128 * 32];

  const int tid  = threadIdx.x;
  const int lane = tid & 63;
  const int wave = tid >> 6;
  const int wr = wave >> 1, wc = wave & 1;       // wave sub-tile (64x64)

  const int tileN = blockIdx.x & 7;              // 8 N tiles
  const int tileM = blockIdx.x >> 3;             // 64 M tiles
  const size_t brow = (size_t)tileM * 128;
  const size_t bcol = (size_t)tileN * 128;

  const __hip_bfloat16* Ab = A  + brow * KTOT;
  const __hip_bfloat16* Bb = Bw + bcol * KTOT;

  // staging: 8 chunks of 1024B per operand; wave handles chunks 2w, 2w+1.
  // lane l of chunk c -> LDS row c*16 + l/4, col (l&3)*8 (linear dest).
  const int c0    = wave * 2;
  const int srow0 = c0 * 16 + (lane >> 2);
  const int scol  = (lane & 3) * 8;

  f32x4 acc[4][4] = {};

  for (int k0 = 0; k0 < KTOT; k0 += 32) {
    load_lds16(Ab + (size_t)srow0 * KTOT + k0 + scol,        &As[c0 * 512]);
    load_lds16(Ab + (size_t)(srow0 + 16) * KTOT + k0 + scol, &As[(c0 + 1) * 512]);
    load_lds16(Bb + (size_t)srow0 * KTOT + k0 + scol,        &Bs[c0 * 512]);
    load_lds16(Bb + (size_t)(srow0 + 16) * KTOT + k0 + scol, &Bs[(c0 + 1) * 512]);
    __syncthreads();   // drains vmcnt -> LDS tiles ready

    const int kq = (lane >> 4) * 8;
    bf16x8 afrag[4], bfrag[4];
#pragma unroll
    for (int mi = 0; mi < 4; ++mi)
      afrag[mi] = *reinterpret_cast<const bf16x8*>(&As[(wr * 64 + mi * 16 + (lane & 15)) * 32 + kq]);
#pragma unroll
    for (int ni = 0; ni < 4; ++ni)
      bfrag[ni] = *reinterpret_cast<const bf16x8*>(&Bs[(wc * 64 + ni * 16 + (lane & 15)) * 32 + kq]);

#pragma unroll
    for (int mi = 0; mi < 4; ++mi)
#pragma unroll
      for (int ni = 0; ni < 4; ++ni)
        acc[mi][ni] = __builtin_amdgcn_mfma_f32_16x16x32_bf16(afrag[mi], bfrag[ni], acc[mi][ni], 0, 0, 0);

    __syncthreads();   // LDS consumed -> safe to restage
  }

  // epilogue: C/D layout col = lane&15, row = (lane>>4)*4 + reg  [m89/m91]
  const int crow0 = (lane >> 4) * 4;
  const int ccol  = lane & 15;
#pragma unroll
  for (int mi = 0; mi < 4; ++mi)
#pragma unroll
    for (int ni = 0; ni < 4; ++ni) {
      const size_t r0 = brow + wr * 64 + mi * 16 + crow0;
      const size_t cc = bcol + wc * 64 + ni * 16 + ccol;
      float* cp = C + r0 * NOUT + cc;
#pragma unroll
      for (int r = 0; r < 4; ++r) cp[(size_t)r * NOUT] = acc[mi][ni][r];
    }
}

// ---------------------------------------------------------------------------
// Kernel 4: in-place rowwise LayerNorm (gamma, beta) + PReLU. One block/row.
// ---------------------------------------------------------------------------
__global__ void ln_prelu(float* __restrict__ y,
                         const float* __restrict__ gamma,
                         const float* __restrict__ beta,
                         const float* __restrict__ pa) {
  const int row = blockIdx.x;
  const int t = threadIdx.x;                 // 256 threads, 4 floats each
  float* yr = y + (size_t)row * NOUT;

  float4 v = reinterpret_cast<const float4*>(yr)[t];
  float s  = v.x + v.y + v.z + v.w;
  float sq = v.x * v.x + v.y * v.y + v.z * v.z + v.w * v.w;
#pragma unroll
  for (int off = 32; off > 0; off >>= 1) {
    s  += __shfl_down(s, off);
    sq += __shfl_down(sq, off);
  }
  __shared__ float red[8];
  const int wave = t >> 6, lane = t & 63;
  if (lane == 0) { red[wave] = s; red[4 + wave] = sq; }
  __syncthreads();
  if (t == 0) {
    const float S = red[0] + red[1] + red[2] + red[3];
    const float Q = red[4] + red[5] + red[6] + red[7];
    const float mu = S * (1.0f / NOUT);
    const float var = Q * (1.0f / NOUT) - mu * mu;
    red[0] = mu;
    red[1] = rsqrtf(var + 1e-5f);
  }
  __syncthreads();
  const float mu = red[0], rs = red[1];
  const float a = pa[0];
  const float4 g4 = reinterpret_cast<const float4*>(gamma)[t];
  const float4 b4 = reinterpret_cast<const float4*>(beta)[t];
  float o0 = (v.x - mu) * rs * g4.x + b4.x;
  float o1 = (v.y - mu) * rs * g4.y + b4.y;
  float o2 = (v.z - mu) * rs * g4.z + b4.z;
  float o3 = (v.w - mu) * rs * g4.w + b4.w;
  v.x = o0 >= 0.0f ? o0 : a * o0;
  v.y = o1 >= 0.0f ? o1 : a * o1;
  v.z = o2 >= 0.0f ? o2 : a * o2;
  v.w = o3 >= 0.0f ? o3 : a * o3;
  reinterpret_cast<float4*>(yr)[t] = v;
}

// ---------------------------------------------------------------------------
extern "C" void kernel_launch(void* const* d_in, const int* in_sizes, int n_in,
                              void* d_out, int out_size, void* d_ws, size_t ws_size,
                              hipStream_t stream) {
  const float* x     = (const float*)d_in[0];
  const float* bw    = (const float*)d_in[1];
  const float* sw    = (const float*)d_in[2];
  const float* grid  = (const float*)d_in[3];
  const float* gamma = (const float*)d_in[4];
  const float* beta  = (const float*)d_in[5];
  const float* pa    = (const float*)d_in[6];
  float* out = (float*)d_out;

  __hip_bfloat16* Abuf = (__hip_bfloat16*)d_ws;                 // 8192 x 9216 bf16
  __hip_bfloat16* Wbuf = Abuf + (size_t)NB * KTOT;              // 1024 x 9216 bf16

  build_A<<<(NB / 8) * NIN / 256, 256, 0, stream>>>(x, grid, Abuf);
  convert_W<<<NOUT * (KTOT / 8) / 256, 256, 0, stream>>>(bw, sw, Wbuf);
  gemm_bt<<<(NB / 128) * (NOUT / 128), 256, 0, stream>>>(Abuf, Wbuf, out);
  ln_prelu<<<NB, 256, 0, stream>>>(out, gamma, beta, pa);
}

// Round 2
// 279.999 us; speedup vs baseline: 1.0503x; 1.0503x over previous
//
#include <hip/hip_runtime.h>
#include <hip/hip_bf16.h>

typedef __attribute__((ext_vector_type(8))) short bf16x8;   // 8 bf16 (4 VGPRs)
typedef __attribute__((ext_vector_type(4))) float f32x4;    // MFMA C/D

#define KTOT 9216   // 1024 (gelu part) + 1024*8 (spline bases part)
#define KHALF 4608  // split-K slice
#define NB   8192
#define NIN  1024
#define NOUT 1024

__device__ __forceinline__ void load_lds16(const void* g, void* l) {
  __builtin_amdgcn_global_load_lds(
      (const __attribute__((address_space(1))) void*)g,
      (__attribute__((address_space(3))) void*)l, 16, 0, 0);
}

// ---------------------------------------------------------------------------
// Kernel 1: A[b, 0:1024] = gelu(x[b,i]) ; A[b, 1024 + i*8 + k] = bspline basis
// ---------------------------------------------------------------------------
__global__ void build_A(const float* __restrict__ x,
                        const float* __restrict__ grid,
                        __hip_bfloat16* __restrict__ A) {
  const int tid = blockIdx.x * blockDim.x + threadIdx.x;   // 0 .. 1048575
  const int i  = tid & (NIN - 1);
  const int b0 = (tid >> 10) << 3;                         // 8 rows / thread

  float g[12];
#pragma unroll
  for (int j = 0; j < 12; ++j) g[j] = grid[j];

  float invdr1[10], invdd1[10], invdr2[9], invdd2[9], invdr3[8], invdd3[8];
#pragma unroll
  for (int j = 0; j < 10; ++j) {
    invdr1[j] = __builtin_amdgcn_rcpf(g[j + 1] - g[j]);
    invdd1[j] = __builtin_amdgcn_rcpf(g[j + 2] - g[j + 1]);
  }
#pragma unroll
  for (int j = 0; j < 9; ++j) {
    invdr2[j] = __builtin_amdgcn_rcpf(g[j + 2] - g[j]);
    invdd2[j] = __builtin_amdgcn_rcpf(g[j + 3] - g[j + 1]);
  }
#pragma unroll
  for (int j = 0; j < 8; ++j) {
    invdr3[j] = __builtin_amdgcn_rcpf(g[j + 3] - g[j]);
    invdd3[j] = __builtin_amdgcn_rcpf(g[j + 4] - g[j + 1]);
  }

  for (int bb = 0; bb < 8; ++bb) {
    const int b = b0 + bb;
    const float xv = x[(size_t)b * NIN + i];
    const float ge = 0.5f * xv * (1.0f + erff(xv * 0.70710678118654752f));
    __hip_bfloat16* Arow = A + (size_t)b * KTOT;
    Arow[i] = __float2bfloat16(ge);

    float bas[11];
#pragma unroll
    for (int j = 0; j < 11; ++j)
      bas[j] = (xv >= g[j] && xv < g[j + 1]) ? 1.0f : 0.0f;
#pragma unroll
    for (int j = 0; j < 10; ++j)   // k = 1
      bas[j] = (xv - g[j]) * invdr1[j] * bas[j] + (g[j + 2] - xv) * invdd1[j] * bas[j + 1];
#pragma unroll
    for (int j = 0; j < 9; ++j)    // k = 2
      bas[j] = (xv - g[j]) * invdr2[j] * bas[j] + (g[j + 3] - xv) * invdd2[j] * bas[j + 1];
#pragma unroll
    for (int j = 0; j < 8; ++j)    // k = 3
      bas[j] = (xv - g[j]) * invdr3[j] * bas[j] + (g[j + 4] - xv) * invdd3[j] * bas[j + 1];

    union { __hip_bfloat16 h[8]; uint4 v; } u;
#pragma unroll
    for (int k = 0; k < 8; ++k) u.h[k] = __float2bfloat16(bas[k]);
    *reinterpret_cast<uint4*>(Arow + NIN + i * 8) = u.v;   // 16B coalesced store
  }
}

// ---------------------------------------------------------------------------
// Kernel 2: W[o, 0:1024] = base_weight[o,:] ; W[o, 1024:] = spline_weight[o,:,:]
// ---------------------------------------------------------------------------
__global__ void convert_W(const float* __restrict__ bw,
                          const float* __restrict__ sw,
                          __hip_bfloat16* __restrict__ W) {
  const int idx = blockIdx.x * blockDim.x + threadIdx.x;   // 0 .. 1179647
  const int o  = idx / 1152;                               // 9216/8 chunks per row
  const int c8 = (idx - o * 1152) * 8;
  const float* src = (c8 < 1024) ? (bw + (size_t)o * 1024 + c8)
                                 : (sw + (size_t)o * 8192 + (c8 - 1024));
  float4 f0 = reinterpret_cast<const float4*>(src)[0];
  float4 f1 = reinterpret_cast<const float4*>(src)[1];
  union { __hip_bfloat16 h[8]; uint4 v; } u;
  u.h[0] = __float2bfloat16(f0.x); u.h[1] = __float2bfloat16(f0.y);
  u.h[2] = __float2bfloat16(f0.z); u.h[3] = __float2bfloat16(f0.w);
  u.h[4] = __float2bfloat16(f1.x); u.h[5] = __float2bfloat16(f1.y);
  u.h[6] = __float2bfloat16(f1.z); u.h[7] = __float2bfloat16(f1.w);
  *reinterpret_cast<uint4*>(W + (size_t)o * KTOT + c8) = u.v;
}

// ---------------------------------------------------------------------------
// Kernel 3: split-K=2 GEMM. C_ks[m,n] = sum_{k in slice ks} A[m,k] * W[n,k]
// m97 structure: 128x128 tile, BK=32, 4 waves, global_load_lds width=16.
// Grid = 64 Mtiles x 8 Ntiles x 2 Kslices = 1024 blocks -> 4 blocks/CU.
// XCD-aware bijective swizzle (1024 % 8 == 0) for A-panel L2 locality.
// ---------------------------------------------------------------------------
__global__ void gemm_bt(const __hip_bfloat16* __restrict__ A,
                        const __hip_bfloat16* __restrict__ Bw,
                        float* __restrict__ P0,
                        float* __restrict__ P1) {
  __shared__ __hip_bfloat16 As[128 * 32];
  __shared__ __hip_bfloat16 Bs[128 * 32];

  const int tid  = threadIdx.x;
  const int lane = tid & 63;
  const int wave = tid >> 6;
  const int wr = wave >> 1, wc = wave & 1;       // wave sub-tile (64x64)

  // bijective XCD swizzle: hardware round-robins blockIdx%8 across XCDs;
  // give each XCD a contiguous chunk of 128 logical tiles.
  const int orig = blockIdx.x;
  const int bid  = (orig & 7) * 128 + (orig >> 3);

  const int ks    = bid & 1;                     // K slice
  const int tileN = (bid >> 1) & 7;              // 8 N tiles
  const int tileM = bid >> 4;                    // 64 M tiles
  const size_t brow = (size_t)tileM * 128;
  const size_t bcol = (size_t)tileN * 128;
  const int kbeg = ks * KHALF;

  const __hip_bfloat16* Ab = A  + brow * KTOT;
  const __hip_bfloat16* Bb = Bw + bcol * KTOT;
  float* C = ks ? P1 : P0;

  // staging: 8 chunks of 1024B per operand; wave handles chunks 2w, 2w+1.
  const int c0    = wave * 2;
  const int srow0 = c0 * 16 + (lane >> 2);
  const int scol  = (lane & 3) * 8;

  f32x4 acc[4][4] = {};

  for (int k0 = kbeg; k0 < kbeg + KHALF; k0 += 32) {
    load_lds16(Ab + (size_t)srow0 * KTOT + k0 + scol,        &As[c0 * 512]);
    load_lds16(Ab + (size_t)(srow0 + 16) * KTOT + k0 + scol, &As[(c0 + 1) * 512]);
    load_lds16(Bb + (size_t)srow0 * KTOT + k0 + scol,        &Bs[c0 * 512]);
    load_lds16(Bb + (size_t)(srow0 + 16) * KTOT + k0 + scol, &Bs[(c0 + 1) * 512]);
    __syncthreads();   // drains vmcnt -> LDS tiles ready

    const int kq = (lane >> 4) * 8;
    bf16x8 afrag[4], bfrag[4];
#pragma unroll
    for (int mi = 0; mi < 4; ++mi)
      afrag[mi] = *reinterpret_cast<const bf16x8*>(&As[(wr * 64 + mi * 16 + (lane & 15)) * 32 + kq]);
#pragma unroll
    for (int ni = 0; ni < 4; ++ni)
      bfrag[ni] = *reinterpret_cast<const bf16x8*>(&Bs[(wc * 64 + ni * 16 + (lane & 15)) * 32 + kq]);

#pragma unroll
    for (int mi = 0; mi < 4; ++mi)
#pragma unroll
      for (int ni = 0; ni < 4; ++ni)
        acc[mi][ni] = __builtin_amdgcn_mfma_f32_16x16x32_bf16(afrag[mi], bfrag[ni], acc[mi][ni], 0, 0, 0);

    __syncthreads();   // LDS consumed -> safe to restage
  }

  // epilogue: C/D layout col = lane&15, row = (lane>>4)*4 + reg  [m89/m91]
  const int crow0 = (lane >> 4) * 4;
  const int ccol  = lane & 15;
#pragma unroll
  for (int mi = 0; mi < 4; ++mi)
#pragma unroll
    for (int ni = 0; ni < 4; ++ni) {
      const size_t r0 = brow + wr * 64 + mi * 16 + crow0;
      const size_t cc = bcol + wc * 64 + ni * 16 + ccol;
      float* cp = C + r0 * NOUT + cc;
#pragma unroll
      for (int r = 0; r < 4; ++r) cp[(size_t)r * NOUT] = acc[mi][ni][r];
    }
}

// ---------------------------------------------------------------------------
// Kernel 4: y = P0 + P1 (split-K reduce), rowwise LayerNorm + PReLU -> y.
// P1 aliases d_out (partial in, final out). One block per row.
// ---------------------------------------------------------------------------
__global__ void reduce_ln_prelu(const float* __restrict__ P0,
                                float* __restrict__ y,
                                const float* __restrict__ gamma,
                                const float* __restrict__ beta,
                                const float* __restrict__ pa) {
  const int row = blockIdx.x;
  const int t = threadIdx.x;                 // 256 threads, 4 floats each
  const float* p0r = P0 + (size_t)row * NOUT;
  float* yr = y + (size_t)row * NOUT;

  float4 a = reinterpret_cast<const float4*>(p0r)[t];
  float4 v = reinterpret_cast<const float4*>(yr)[t];
  v.x += a.x; v.y += a.y; v.z += a.z; v.w += a.w;

  float s  = v.x + v.y + v.z + v.w;
  float sq = v.x * v.x + v.y * v.y + v.z * v.z + v.w * v.w;
#pragma unroll
  for (int off = 32; off > 0; off >>= 1) {
    s  += __shfl_down(s, off);
    sq += __shfl_down(sq, off);
  }
  __shared__ float red[8];
  const int wv = t >> 6, lane = t & 63;
  if (lane == 0) { red[wv] = s; red[4 + wv] = sq; }
  __syncthreads();
  if (t == 0) {
    const float S = red[0] + red[1] + red[2] + red[3];
    const float Q = red[4] + red[5] + red[6] + red[7];
    const float mu = S * (1.0f / NOUT);
    const float var = Q * (1.0f / NOUT) - mu * mu;
    red[0] = mu;
    red[1] = rsqrtf(var + 1e-5f);
  }
  __syncthreads();
  const float mu = red[0], rs = red[1];
  const float aP = pa[0];
  const float4 g4 = reinterpret_cast<const float4*>(gamma)[t];
  const float4 b4 = reinterpret_cast<const float4*>(beta)[t];
  float o0 = (v.x - mu) * rs * g4.x + b4.x;
  float o1 = (v.y - mu) * rs * g4.y + b4.y;
  float o2 = (v.z - mu) * rs * g4.z + b4.z;
  float o3 = (v.w - mu) * rs * g4.w + b4.w;
  v.x = o0 >= 0.0f ? o0 : aP * o0;
  v.y = o1 >= 0.0f ? o1 : aP * o1;
  v.z = o2 >= 0.0f ? o2 : aP * o2;
  v.w = o3 >= 0.0f ? o3 : aP * o3;
  reinterpret_cast<float4*>(yr)[t] = v;
}

// ---------------------------------------------------------------------------
extern "C" void kernel_launch(void* const* d_in, const int* in_sizes, int n_in,
                              void* d_out, int out_size, void* d_ws, size_t ws_size,
                              hipStream_t stream) {
  const float* x     = (const float*)d_in[0];
  const float* bw    = (const float*)d_in[1];
  const float* sw    = (const float*)d_in[2];
  const float* grid  = (const float*)d_in[3];
  const float* gamma = (const float*)d_in[4];
  const float* beta  = (const float*)d_in[5];
  const float* pa    = (const float*)d_in[6];
  float* out = (float*)d_out;

  __hip_bfloat16* Abuf = (__hip_bfloat16*)d_ws;                 // 8192 x 9216 bf16
  __hip_bfloat16* Wbuf = Abuf + (size_t)NB * KTOT;              // 1024 x 9216 bf16
  float* P0 = (float*)(Wbuf + (size_t)NOUT * KTOT);             // 8192 x 1024 f32 partial

  build_A<<<(NB / 8) * NIN / 256, 256, 0, stream>>>(x, grid, Abuf);
  convert_W<<<NOUT * (KTOT / 8) / 256, 256, 0, stream>>>(bw, sw, Wbuf);
  gemm_bt<<<(NB / 128) * (NOUT / 128) * 2, 256, 0, stream>>>(Abuf, Wbuf, P0, out);
  reduce_ln_prelu<<<NB, 256, 0, stream>>>(P0, out, gamma, beta, pa);
}

// Round 3
// 267.077 us; speedup vs baseline: 1.1012x; 1.0484x over previous
//
#include <hip/hip_runtime.h>
#include <hip/hip_bf16.h>

typedef __attribute__((ext_vector_type(8))) short bf16x8;   // 8 bf16 (4 VGPRs)
typedef __attribute__((ext_vector_type(4))) float f32x4;    // MFMA C/D

#define KTOT 9216   // 1024 (gelu part) + 1024*8 (spline bases part)
#define NB   8192
#define NIN  1024
#define NOUT 1024
#define NT   288    // K-steps of 32

__device__ __forceinline__ void load_lds16(const void* g, void* l) {
  __builtin_amdgcn_global_load_lds(
      (const __attribute__((address_space(1))) void*)g,
      (__attribute__((address_space(3))) void*)l, 16, 0, 0);
}

// ---------------------------------------------------------------------------
// Kernel 1: A[b, 0:1024] = gelu(x[b,i]) ; A[b, 1024 + i*8 + k] = bspline basis
// ---------------------------------------------------------------------------
__global__ void build_A(const float* __restrict__ x,
                        const float* __restrict__ grid,
                        __hip_bfloat16* __restrict__ A) {
  const int tid = blockIdx.x * blockDim.x + threadIdx.x;
  const int i  = tid & (NIN - 1);
  const int b0 = (tid >> 10) << 3;                         // 8 rows / thread

  float g[12];
#pragma unroll
  for (int j = 0; j < 12; ++j) g[j] = grid[j];

  float invdr1[10], invdd1[10], invdr2[9], invdd2[9], invdr3[8], invdd3[8];
#pragma unroll
  for (int j = 0; j < 10; ++j) {
    invdr1[j] = __builtin_amdgcn_rcpf(g[j + 1] - g[j]);
    invdd1[j] = __builtin_amdgcn_rcpf(g[j + 2] - g[j + 1]);
  }
#pragma unroll
  for (int j = 0; j < 9; ++j) {
    invdr2[j] = __builtin_amdgcn_rcpf(g[j + 2] - g[j]);
    invdd2[j] = __builtin_amdgcn_rcpf(g[j + 3] - g[j + 1]);
  }
#pragma unroll
  for (int j = 0; j < 8; ++j) {
    invdr3[j] = __builtin_amdgcn_rcpf(g[j + 3] - g[j]);
    invdd3[j] = __builtin_amdgcn_rcpf(g[j + 4] - g[j + 1]);
  }

  for (int bb = 0; bb < 8; ++bb) {
    const int b = b0 + bb;
    const float xv = x[(size_t)b * NIN + i];
    const float ge = 0.5f * xv * (1.0f + erff(xv * 0.70710678118654752f));
    __hip_bfloat16* Arow = A + (size_t)b * KTOT;
    Arow[i] = __float2bfloat16(ge);

    float bas[11];
#pragma unroll
    for (int j = 0; j < 11; ++j)
      bas[j] = (xv >= g[j] && xv < g[j + 1]) ? 1.0f : 0.0f;
#pragma unroll
    for (int j = 0; j < 10; ++j)
      bas[j] = (xv - g[j]) * invdr1[j] * bas[j] + (g[j + 2] - xv) * invdd1[j] * bas[j + 1];
#pragma unroll
    for (int j = 0; j < 9; ++j)
      bas[j] = (xv - g[j]) * invdr2[j] * bas[j] + (g[j + 3] - xv) * invdd2[j] * bas[j + 1];
#pragma unroll
    for (int j = 0; j < 8; ++j)
      bas[j] = (xv - g[j]) * invdr3[j] * bas[j] + (g[j + 4] - xv) * invdd3[j] * bas[j + 1];

    union { __hip_bfloat16 h[8]; uint4 v; } u;
#pragma unroll
    for (int k = 0; k < 8; ++k) u.h[k] = __float2bfloat16(bas[k]);
    *reinterpret_cast<uint4*>(Arow + NIN + i * 8) = u.v;
  }
}

// ---------------------------------------------------------------------------
// Kernel 2: W[o, 0:1024] = base_weight[o,:] ; W[o, 1024:] = spline_weight[o,:,:]
// ---------------------------------------------------------------------------
__global__ void convert_W(const float* __restrict__ bw,
                          const float* __restrict__ sw,
                          __hip_bfloat16* __restrict__ W) {
  const int idx = blockIdx.x * blockDim.x + threadIdx.x;
  const int o  = idx / 1152;
  const int c8 = (idx - o * 1152) * 8;
  const float* src = (c8 < 1024) ? (bw + (size_t)o * 1024 + c8)
                                 : (sw + (size_t)o * 8192 + (c8 - 1024));
  float4 f0 = reinterpret_cast<const float4*>(src)[0];
  float4 f1 = reinterpret_cast<const float4*>(src)[1];
  union { __hip_bfloat16 h[8]; uint4 v; } u;
  u.h[0] = __float2bfloat16(f0.x); u.h[1] = __float2bfloat16(f0.y);
  u.h[2] = __float2bfloat16(f0.z); u.h[3] = __float2bfloat16(f0.w);
  u.h[4] = __float2bfloat16(f1.x); u.h[5] = __float2bfloat16(f1.y);
  u.h[6] = __float2bfloat16(f1.z); u.h[7] = __float2bfloat16(f1.w);
  *reinterpret_cast<uint4*>(W + (size_t)o * KTOT + c8) = u.v;
}

// ---------------------------------------------------------------------------
// Kernel 3: ring-4 pipelined GEMM (T3+T4+T5).
// BM=256, BN=128, BK=32. 8 waves (4M x 2N), per-wave 64x64 output.
// LDS: 4-deep ring per operand (96 KB). While computing K-tile t, tiles
// t+1,t+2 are in flight/landed, tile t+3 is being issued -> vmcnt(8) gates
// tile t+1 (4 loads each for t+2,t+3 allowed outstanding). Never vmcnt(0)
// in the main loop. 2 barriers/step, no drain.
// Grid 32 Mtiles x 8 Ntiles = 256 blocks; XCD swizzle gives each XCD one
// N-panel (2.36 MB B panel resident in its 4 MB L2).
// ---------------------------------------------------------------------------
__global__ __launch_bounds__(512, 1)
void gemm_pipe(const __hip_bfloat16* __restrict__ A,
               const __hip_bfloat16* __restrict__ Bw,
               float* __restrict__ C) {
  __shared__ __hip_bfloat16 As[4][256][32];   // 64 KB
  __shared__ __hip_bfloat16 Bs[4][128][32];   // 32 KB

  const int tid  = threadIdx.x;
  const int lane = tid & 63;
  const int wave = tid >> 6;
  const int wr = wave >> 1;          // 0..3 -> M sub-rows (64 each)
  const int wc = wave & 1;           // 0..1 -> N sub-cols (64 each)

  const int orig = blockIdx.x;                    // 256 blocks
  const int bid  = (orig & 7) * 32 + (orig >> 3); // bijective XCD chunking
  const int tileM = bid & 31;
  const int tileN = bid >> 5;                     // XCD x owns N-panel x
  const size_t brow = (size_t)tileM * 256;
  const size_t bcol = (size_t)tileN * 128;

  const __hip_bfloat16* Ab = A  + brow * KTOT;
  const __hip_bfloat16* Bb = Bw + bcol * KTOT;

  // staging source pointers (lane-level, k0=0): 4 threads/row, 16B each
  const int srow = wave * 16 + (lane >> 2);       // 0..127
  const int scol = (lane & 3) * 8;
  const __hip_bfloat16* pa0 = Ab + (size_t)srow * KTOT + scol;          // A rows 0-127
  const __hip_bfloat16* pa1 = Ab + (size_t)(srow + 128) * KTOT + scol;  // A rows 128-255
  const __hip_bfloat16* pb0 = Bb + (size_t)srow * KTOT + scol;          // B rows 0-127

  const int fr = lane & 15;
  const int kq = (lane >> 4) * 8;

  f32x4 acc[4][4] = {};

  // stage K-tile t into ring slot sb (wave-uniform LDS base + lane*16 = linear)
  auto stage = [&](int t, int sb) {
    const size_t ko = (size_t)t * 32;
    load_lds16(pa0 + ko, &As[sb][wave * 16][0]);
    load_lds16(pa1 + ko, &As[sb][128 + wave * 16][0]);
    load_lds16(pb0 + ko, &Bs[sb][wave * 16][0]);
  };

  // prologue: tiles 0,1,2 in flight; gate tile 0 (vmcnt(8) leaves 1,2 in flight)
  stage(0, 0);
  stage(1, 1);
  stage(2, 2);
  asm volatile("s_waitcnt vmcnt(8)" ::: "memory");
  __builtin_amdgcn_s_barrier();
  asm volatile("" ::: "memory");

#define KSTEP(T, BUF, DOSTAGE, VMASM)                                          \
  do {                                                                         \
    bf16x8 af[4], bf[4];                                                       \
    _Pragma("unroll")                                                          \
    for (int mi = 0; mi < 4; ++mi)                                             \
      af[mi] = *reinterpret_cast<const bf16x8*>(&As[BUF][wr * 64 + mi * 16 + fr][kq]); \
    _Pragma("unroll")                                                          \
    for (int ni = 0; ni < 4; ++ni)                                             \
      bf[ni] = *reinterpret_cast<const bf16x8*>(&Bs[BUF][wc * 64 + ni * 16 + fr][kq]); \
    if (DOSTAGE) stage((T) + 3, ((BUF) + 3) & 3);                              \
    asm volatile(VMASM ::: "memory");                                          \
    __builtin_amdgcn_s_barrier();                                              \
    asm volatile("" ::: "memory");                                             \
    __builtin_amdgcn_s_setprio(1);                                             \
    _Pragma("unroll")                                                          \
    for (int mi = 0; mi < 4; ++mi)                                             \
      _Pragma("unroll")                                                        \
      for (int ni = 0; ni < 4; ++ni)                                           \
        acc[mi][ni] = __builtin_amdgcn_mfma_f32_16x16x32_bf16(af[mi], bf[ni],  \
                                                              acc[mi][ni], 0, 0, 0); \
    __builtin_amdgcn_s_setprio(0);                                             \
    asm volatile("" ::: "memory");                                             \
    __builtin_amdgcn_s_barrier();                                              \
    asm volatile("" ::: "memory");                                             \
  } while (0)

  // main loop: t = 0 .. 283 (always stage t+3, vmcnt(8))
  for (int it = 0; it < 71; ++it) {
    const int t0 = it * 4;
    KSTEP(t0 + 0, 0, true, "s_waitcnt vmcnt(8)");
    KSTEP(t0 + 1, 1, true, "s_waitcnt vmcnt(8)");
    KSTEP(t0 + 2, 2, true, "s_waitcnt vmcnt(8)");
    KSTEP(t0 + 3, 3, true, "s_waitcnt vmcnt(8)");
  }
  // tail: t = 284 (stages tile 287) .. 287, derived waits
  KSTEP(284, 0, true,  "s_waitcnt vmcnt(8)");
  KSTEP(285, 1, false, "s_waitcnt vmcnt(4)");
  KSTEP(286, 2, false, "s_waitcnt vmcnt(0)");
  KSTEP(287, 3, false, "s_nop 0");
#undef KSTEP

  // epilogue: C/D layout col = lane&15, row = (lane>>4)*4 + reg
  const int crow0 = (lane >> 4) * 4;
#pragma unroll
  for (int mi = 0; mi < 4; ++mi)
#pragma unroll
    for (int ni = 0; ni < 4; ++ni) {
      const size_t r0 = brow + wr * 64 + mi * 16 + crow0;
      const size_t cc = bcol + wc * 64 + ni * 16 + fr;
      float* cp = C + r0 * NOUT + cc;
#pragma unroll
      for (int r = 0; r < 4; ++r) cp[(size_t)r * NOUT] = acc[mi][ni][r];
    }
}

// ---------------------------------------------------------------------------
// Kernel 4: in-place rowwise LayerNorm + PReLU. One block per row.
// ---------------------------------------------------------------------------
__global__ void ln_prelu(float* __restrict__ y,
                         const float* __restrict__ gamma,
                         const float* __restrict__ beta,
                         const float* __restrict__ pa) {
  const int row = blockIdx.x;
  const int t = threadIdx.x;                 // 256 threads, 4 floats each
  float* yr = y + (size_t)row * NOUT;

  float4 v = reinterpret_cast<const float4*>(yr)[t];
  float s  = v.x + v.y + v.z + v.w;
  float sq = v.x * v.x + v.y * v.y + v.z * v.z + v.w * v.w;
#pragma unroll
  for (int off = 32; off > 0; off >>= 1) {
    s  += __shfl_down(s, off);
    sq += __shfl_down(sq, off);
  }
  __shared__ float red[8];
  const int wv = t >> 6, lane = t & 63;
  if (lane == 0) { red[wv] = s; red[4 + wv] = sq; }
  __syncthreads();
  if (t == 0) {
    const float S = red[0] + red[1] + red[2] + red[3];
    const float Q = red[4] + red[5] + red[6] + red[7];
    const float mu = S * (1.0f / NOUT);
    const float var = Q * (1.0f / NOUT) - mu * mu;
    red[0] = mu;
    red[1] = rsqrtf(var + 1e-5f);
  }
  __syncthreads();
  const float mu = red[0], rs = red[1];
  const float a = pa[0];
  const float4 g4 = reinterpret_cast<const float4*>(gamma)[t];
  const float4 b4 = reinterpret_cast<const float4*>(beta)[t];
  float o0 = (v.x - mu) * rs * g4.x + b4.x;
  float o1 = (v.y - mu) * rs * g4.y + b4.y;
  float o2 = (v.z - mu) * rs * g4.z + b4.z;
  float o3 = (v.w - mu) * rs * g4.w + b4.w;
  v.x = o0 >= 0.0f ? o0 : a * o0;
  v.y = o1 >= 0.0f ? o1 : a * o1;
  v.z = o2 >= 0.0f ? o2 : a * o2;
  v.w = o3 >= 0.0f ? o3 : a * o3;
  reinterpret_cast<float4*>(yr)[t] = v;
}

// ---------------------------------------------------------------------------
extern "C" void kernel_launch(void* const* d_in, const int* in_sizes, int n_in,
                              void* d_out, int out_size, void* d_ws, size_t ws_size,
                              hipStream_t stream) {
  const float* x     = (const float*)d_in[0];
  const float* bw    = (const float*)d_in[1];
  const float* sw    = (const float*)d_in[2];
  const float* grid  = (const float*)d_in[3];
  const float* gamma = (const float*)d_in[4];
  const float* beta  = (const float*)d_in[5];
  const float* pa    = (const float*)d_in[6];
  float* out = (float*)d_out;

  __hip_bfloat16* Abuf = (__hip_bfloat16*)d_ws;                 // 8192 x 9216 bf16
  __hip_bfloat16* Wbuf = Abuf + (size_t)NB * KTOT;              // 1024 x 9216 bf16

  build_A<<<(NB / 8) * NIN / 256, 256, 0, stream>>>(x, grid, Abuf);
  convert_W<<<NOUT * (KTOT / 8) / 256, 256, 0, stream>>>(bw, sw, Wbuf);
  gemm_pipe<<<(NB / 256) * (NOUT / 128), 512, 0, stream>>>(Abuf, Wbuf, out);
  ln_prelu<<<NB, 256, 0, stream>>>(out, gamma, beta, pa);
}

// Round 4
// 236.155 us; speedup vs baseline: 1.2453x; 1.1309x over previous
//
#include <hip/hip_runtime.h>
#include <hip/hip_bf16.h>

typedef __attribute__((ext_vector_type(8))) short bf16x8;   // 8 bf16 (4 VGPRs)
typedef __attribute__((ext_vector_type(4))) float f32x4;    // MFMA C/D

#define KTOT 9216   // 1024 (gelu part) + 1024*8 (spline bases part)
#define KHALF 4608  // split-K slice
#define NB   8192
#define NIN  1024
#define NOUT 1024
#define NTS  144    // K-steps of 32 per slice

__device__ __forceinline__ void load_lds16(const void* g, void* l) {
  __builtin_amdgcn_global_load_lds(
      (const __attribute__((address_space(1))) void*)g,
      (__attribute__((address_space(3))) void*)l, 16, 0, 0);
}

// ---------------------------------------------------------------------------
// Kernel 1: A[b, 0:1024] = gelu(x[b,i]) ; A[b, 1024 + i*8 + k] = bspline basis
// ---------------------------------------------------------------------------
__global__ void build_A(const float* __restrict__ x,
                        const float* __restrict__ grid,
                        __hip_bfloat16* __restrict__ A) {
  const int tid = blockIdx.x * blockDim.x + threadIdx.x;
  const int i  = tid & (NIN - 1);
  const int b0 = (tid >> 10) << 3;                         // 8 rows / thread

  float g[12];
#pragma unroll
  for (int j = 0; j < 12; ++j) g[j] = grid[j];

  float invdr1[10], invdd1[10], invdr2[9], invdd2[9], invdr3[8], invdd3[8];
#pragma unroll
  for (int j = 0; j < 10; ++j) {
    invdr1[j] = __builtin_amdgcn_rcpf(g[j + 1] - g[j]);
    invdd1[j] = __builtin_amdgcn_rcpf(g[j + 2] - g[j + 1]);
  }
#pragma unroll
  for (int j = 0; j < 9; ++j) {
    invdr2[j] = __builtin_amdgcn_rcpf(g[j + 2] - g[j]);
    invdd2[j] = __builtin_amdgcn_rcpf(g[j + 3] - g[j + 1]);
  }
#pragma unroll
  for (int j = 0; j < 8; ++j) {
    invdr3[j] = __builtin_amdgcn_rcpf(g[j + 3] - g[j]);
    invdd3[j] = __builtin_amdgcn_rcpf(g[j + 4] - g[j + 1]);
  }

  for (int bb = 0; bb < 8; ++bb) {
    const int b = b0 + bb;
    const float xv = x[(size_t)b * NIN + i];
    const float ge = 0.5f * xv * (1.0f + erff(xv * 0.70710678118654752f));
    __hip_bfloat16* Arow = A + (size_t)b * KTOT;
    Arow[i] = __float2bfloat16(ge);

    float bas[11];
#pragma unroll
    for (int j = 0; j < 11; ++j)
      bas[j] = (xv >= g[j] && xv < g[j + 1]) ? 1.0f : 0.0f;
#pragma unroll
    for (int j = 0; j < 10; ++j)
      bas[j] = (xv - g[j]) * invdr1[j] * bas[j] + (g[j + 2] - xv) * invdd1[j] * bas[j + 1];
#pragma unroll
    for (int j = 0; j < 9; ++j)
      bas[j] = (xv - g[j]) * invdr2[j] * bas[j] + (g[j + 3] - xv) * invdd2[j] * bas[j + 1];
#pragma unroll
    for (int j = 0; j < 8; ++j)
      bas[j] = (xv - g[j]) * invdr3[j] * bas[j] + (g[j + 4] - xv) * invdd3[j] * bas[j + 1];

    union { __hip_bfloat16 h[8]; uint4 v; } u;
#pragma unroll
    for (int k = 0; k < 8; ++k) u.h[k] = __float2bfloat16(bas[k]);
    *reinterpret_cast<uint4*>(Arow + NIN + i * 8) = u.v;
  }
}

// ---------------------------------------------------------------------------
// Kernel 2: W[o, 0:1024] = base_weight[o,:] ; W[o, 1024:] = spline_weight[o,:,:]
// ---------------------------------------------------------------------------
__global__ void convert_W(const float* __restrict__ bw,
                          const float* __restrict__ sw,
                          __hip_bfloat16* __restrict__ W) {
  const int idx = blockIdx.x * blockDim.x + threadIdx.x;
  const int o  = idx / 1152;
  const int c8 = (idx - o * 1152) * 8;
  const float* src = (c8 < 1024) ? (bw + (size_t)o * 1024 + c8)
                                 : (sw + (size_t)o * 8192 + (c8 - 1024));
  float4 f0 = reinterpret_cast<const float4*>(src)[0];
  float4 f1 = reinterpret_cast<const float4*>(src)[1];
  union { __hip_bfloat16 h[8]; uint4 v; } u;
  u.h[0] = __float2bfloat16(f0.x); u.h[1] = __float2bfloat16(f0.y);
  u.h[2] = __float2bfloat16(f0.z); u.h[3] = __float2bfloat16(f0.w);
  u.h[4] = __float2bfloat16(f1.x); u.h[5] = __float2bfloat16(f1.y);
  u.h[6] = __float2bfloat16(f1.z); u.h[7] = __float2bfloat16(f1.w);
  *reinterpret_cast<uint4*>(W + (size_t)o * KTOT + c8) = u.v;
}

// ---------------------------------------------------------------------------
// Kernel 3: ring-4 pipelined GEMM, 256x256 tile, BK=32, split-K=2.
// 8 waves (2M x 4N), per-wave 128x64 output (acc[8][4]).
// LDS ring of 4 K-tiles per operand (128 KB total). Stage = 4 loads/thread.
// Derived waits: after issuing stage T+3, outstanding = stages T+1..T+3 = 12
// loads; vmcnt(8) drains exactly stage T+1, and the following barrier
// publishes it to all waves before step T+1 reads it. Never vmcnt(0) in the
// main loop. Tail: vmcnt(8)/(4)/(0).
// Grid 32 Mtiles x 4 Ntiles x 2 Kslices = 256 blocks (1/CU). XCD swizzle:
// consecutive-bid chunks vary (N, ks) fastest -> each XCD owns 4 M-tiles
// (18.9 MB A-chunk) x all N x both slices (R2-proven orientation).
// ---------------------------------------------------------------------------
__global__ __launch_bounds__(512, 1)
void gemm_pipe(const __hip_bfloat16* __restrict__ A,
               const __hip_bfloat16* __restrict__ Bw,
               float* __restrict__ P0,
               float* __restrict__ P1) {
  __shared__ __hip_bfloat16 As[4][256][32];   // 64 KB
  __shared__ __hip_bfloat16 Bs[4][256][32];   // 64 KB

  const int tid  = threadIdx.x;
  const int lane = tid & 63;
  const int wave = tid >> 6;
  const int wr = wave >> 2;          // 0..1 -> M half (128 rows)
  const int wc = wave & 3;           // 0..3 -> N quarter (64 cols)

  const int orig = blockIdx.x;                    // 256 blocks
  const int bid  = (orig & 7) * 32 + (orig >> 3); // bijective XCD chunking
  const int ks    = bid & 1;                      // K slice
  const int tileN = (bid >> 1) & 3;               // 4 N tiles
  const int tileM = bid >> 3;                     // 32 M tiles
  const size_t brow = (size_t)tileM * 256;
  const size_t bcol = (size_t)tileN * 256;
  const int kbeg = ks * KHALF;

  const __hip_bfloat16* Ab = A  + brow * KTOT;
  const __hip_bfloat16* Bb = Bw + bcol * KTOT;
  float* C = ks ? P1 : P0;

  // staging source (lane-level): 4 threads/row, 16B each; wave w covers rows
  // 16w..16w+15 (and +128) -> LDS dest wave-uniform base + lane*16 (linear).
  const int srow = wave * 16 + (lane >> 2);       // 0..127
  const int scol = (lane & 3) * 8;
  const __hip_bfloat16* pa0 = Ab + (size_t)srow * KTOT + kbeg + scol;
  const __hip_bfloat16* pa1 = Ab + (size_t)(srow + 128) * KTOT + kbeg + scol;
  const __hip_bfloat16* pb0 = Bb + (size_t)srow * KTOT + kbeg + scol;
  const __hip_bfloat16* pb1 = Bb + (size_t)(srow + 128) * KTOT + kbeg + scol;

  const int fr = lane & 15;
  const int kq = (lane >> 4) * 8;

  f32x4 acc[8][4] = {};

  auto stage = [&](int t, int sb) {
    const size_t ko = (size_t)t * 32;
    load_lds16(pa0 + ko, &As[sb][wave * 16][0]);
    load_lds16(pa1 + ko, &As[sb][128 + wave * 16][0]);
    load_lds16(pb0 + ko, &Bs[sb][wave * 16][0]);
    load_lds16(pb1 + ko, &Bs[sb][128 + wave * 16][0]);
  };

  // prologue: stage tiles 0,1,2 (12 loads); drain stage 0, publish.
  stage(0, 0);
  stage(1, 1);
  stage(2, 2);
  asm volatile("s_waitcnt vmcnt(8)" ::: "memory");
  __builtin_amdgcn_s_barrier();
  asm volatile("" ::: "memory");

#define KSTEP(T, BUF, DOSTAGE, VMASM)                                          \
  do {                                                                         \
    bf16x8 af[8], bf[4];                                                       \
    _Pragma("unroll")                                                          \
    for (int mi = 0; mi < 8; ++mi)                                             \
      af[mi] = *reinterpret_cast<const bf16x8*>(&As[BUF][wr * 128 + mi * 16 + fr][kq]); \
    _Pragma("unroll")                                                          \
    for (int ni = 0; ni < 4; ++ni)                                             \
      bf[ni] = *reinterpret_cast<const bf16x8*>(&Bs[BUF][wc * 64 + ni * 16 + fr][kq]); \
    if (DOSTAGE) stage((T) + 3, ((BUF) + 3) & 3);                              \
    asm volatile(VMASM ::: "memory");                                          \
    __builtin_amdgcn_s_barrier();                                              \
    asm volatile("" ::: "memory");                                             \
    __builtin_amdgcn_s_setprio(1);                                             \
    _Pragma("unroll")                                                          \
    for (int mi = 0; mi < 8; ++mi)                                             \
      _Pragma("unroll")                                                        \
      for (int ni = 0; ni < 4; ++ni)                                           \
        acc[mi][ni] = __builtin_amdgcn_mfma_f32_16x16x32_bf16(af[mi], bf[ni],  \
                                                              acc[mi][ni], 0, 0, 0); \
    __builtin_amdgcn_s_setprio(0);                                             \
    asm volatile("" ::: "memory");                                             \
    __builtin_amdgcn_s_barrier();                                              \
    asm volatile("" ::: "memory");                                             \
  } while (0)

  // main: steps 0..139 (each stages t+3 <= 142)
  for (int it = 0; it < 35; ++it) {
    const int t0 = it * 4;
    KSTEP(t0 + 0, 0, true, "s_waitcnt vmcnt(8)");
    KSTEP(t0 + 1, 1, true, "s_waitcnt vmcnt(8)");
    KSTEP(t0 + 2, 2, true, "s_waitcnt vmcnt(8)");
    KSTEP(t0 + 3, 3, true, "s_waitcnt vmcnt(8)");
  }
  // tail: step 140 stages 143; then derived drains.
  KSTEP(140, 0, true,  "s_waitcnt vmcnt(8)");
  KSTEP(141, 1, false, "s_waitcnt vmcnt(4)");
  KSTEP(142, 2, false, "s_waitcnt vmcnt(0)");
  KSTEP(143, 3, false, "s_nop 0");
#undef KSTEP

  // epilogue: C/D layout col = lane&15, row = (lane>>4)*4 + reg
  const int crow0 = (lane >> 4) * 4;
#pragma unroll
  for (int mi = 0; mi < 8; ++mi)
#pragma unroll
    for (int ni = 0; ni < 4; ++ni) {
      const size_t r0 = brow + wr * 128 + mi * 16 + crow0;
      const size_t cc = bcol + wc * 64 + ni * 16 + fr;
      float* cp = C + r0 * NOUT + cc;
#pragma unroll
      for (int r = 0; r < 4; ++r) cp[(size_t)r * NOUT] = acc[mi][ni][r];
    }
}

// ---------------------------------------------------------------------------
// Kernel 4: y = P0 + P1 (split-K reduce), rowwise LayerNorm + PReLU -> y.
// P1 aliases d_out. One block per row.
// ---------------------------------------------------------------------------
__global__ void reduce_ln_prelu(const float* __restrict__ P0,
                                float* __restrict__ y,
                                const float* __restrict__ gamma,
                                const float* __restrict__ beta,
                                const float* __restrict__ pa) {
  const int row = blockIdx.x;
  const int t = threadIdx.x;                 // 256 threads, 4 floats each
  const float* p0r = P0 + (size_t)row * NOUT;
  float* yr = y + (size_t)row * NOUT;

  float4 a = reinterpret_cast<const float4*>(p0r)[t];
  float4 v = reinterpret_cast<const float4*>(yr)[t];
  v.x += a.x; v.y += a.y; v.z += a.z; v.w += a.w;

  float s  = v.x + v.y + v.z + v.w;
  float sq = v.x * v.x + v.y * v.y + v.z * v.z + v.w * v.w;
#pragma unroll
  for (int off = 32; off > 0; off >>= 1) {
    s  += __shfl_down(s, off);
    sq += __shfl_down(sq, off);
  }
  __shared__ float red[8];
  const int wv = t >> 6, lane = t & 63;
  if (lane == 0) { red[wv] = s; red[4 + wv] = sq; }
  __syncthreads();
  if (t == 0) {
    const float S = red[0] + red[1] + red[2] + red[3];
    const float Q = red[4] + red[5] + red[6] + red[7];
    const float mu = S * (1.0f / NOUT);
    const float var = Q * (1.0f / NOUT) - mu * mu;
    red[0] = mu;
    red[1] = rsqrtf(var + 1e-5f);
  }
  __syncthreads();
  const float mu = red[0], rs = red[1];
  const float aP = pa[0];
  const float4 g4 = reinterpret_cast<const float4*>(gamma)[t];
  const float4 b4 = reinterpret_cast<const float4*>(beta)[t];
  float o0 = (v.x - mu) * rs * g4.x + b4.x;
  float o1 = (v.y - mu) * rs * g4.y + b4.y;
  float o2 = (v.z - mu) * rs * g4.z + b4.z;
  float o3 = (v.w - mu) * rs * g4.w + b4.w;
  v.x = o0 >= 0.0f ? o0 : aP * o0;
  v.y = o1 >= 0.0f ? o1 : aP * o1;
  v.z = o2 >= 0.0f ? o2 : aP * o2;
  v.w = o3 >= 0.0f ? o3 : aP * o3;
  reinterpret_cast<float4*>(yr)[t] = v;
}

// ---------------------------------------------------------------------------
extern "C" void kernel_launch(void* const* d_in, const int* in_sizes, int n_in,
                              void* d_out, int out_size, void* d_ws, size_t ws_size,
                              hipStream_t stream) {
  const float* x     = (const float*)d_in[0];
  const float* bw    = (const float*)d_in[1];
  const float* sw    = (const float*)d_in[2];
  const float* grid  = (const float*)d_in[3];
  const float* gamma = (const float*)d_in[4];
  const float* beta  = (const float*)d_in[5];
  const float* pa    = (const float*)d_in[6];
  float* out = (float*)d_out;

  __hip_bfloat16* Abuf = (__hip_bfloat16*)d_ws;                 // 8192 x 9216 bf16
  __hip_bfloat16* Wbuf = Abuf + (size_t)NB * KTOT;              // 1024 x 9216 bf16
  float* P0 = (float*)(Wbuf + (size_t)NOUT * KTOT);             // 8192 x 1024 f32

  build_A<<<(NB / 8) * NIN / 256, 256, 0, stream>>>(x, grid, Abuf);
  convert_W<<<NOUT * (KTOT / 8) / 256, 256, 0, stream>>>(bw, sw, Wbuf);
  gemm_pipe<<<(NB / 256) * (NOUT / 256) * 2, 512, 0, stream>>>(Abuf, Wbuf, P0, out);
  reduce_ln_prelu<<<NB, 256, 0, stream>>>(P0, out, gamma, beta, pa);
}

// Round 5
// 209.451 us; speedup vs baseline: 1.4041x; 1.1275x over previous
//
#include <hip/hip_runtime.h>
#include <hip/hip_bf16.h>

typedef __attribute__((ext_vector_type(8))) short bf16x8;   // 8 bf16 (4 VGPRs)
typedef __attribute__((ext_vector_type(4))) float f32x4;    // MFMA C/D

#define KTOT 9216   // 1024 (gelu part) + 1024*8 (spline bases part)
#define KHALF 4608  // split-K slice
#define NB   8192
#define NIN  1024
#define NOUT 1024
#define NTILE 72    // K-tiles of 64 per slice

__device__ __forceinline__ void load_lds16(const void* g, void* l) {
  __builtin_amdgcn_global_load_lds(
      (const __attribute__((address_space(1))) void*)g,
      (__attribute__((address_space(3))) void*)l, 16, 0, 0);
}

// ---------------------------------------------------------------------------
// Kernel 1: A[b, 0:1024] = gelu(x[b,i]) ; A[b, 1024 + i*8 + k] = bspline basis
// ---------------------------------------------------------------------------
__global__ void build_A(const float* __restrict__ x,
                        const float* __restrict__ grid,
                        __hip_bfloat16* __restrict__ A) {
  const int tid = blockIdx.x * blockDim.x + threadIdx.x;
  const int i  = tid & (NIN - 1);
  const int b0 = (tid >> 10) << 3;                         // 8 rows / thread

  float g[12];
#pragma unroll
  for (int j = 0; j < 12; ++j) g[j] = grid[j];

  float invdr1[10], invdd1[10], invdr2[9], invdd2[9], invdr3[8], invdd3[8];
#pragma unroll
  for (int j = 0; j < 10; ++j) {
    invdr1[j] = __builtin_amdgcn_rcpf(g[j + 1] - g[j]);
    invdd1[j] = __builtin_amdgcn_rcpf(g[j + 2] - g[j + 1]);
  }
#pragma unroll
  for (int j = 0; j < 9; ++j) {
    invdr2[j] = __builtin_amdgcn_rcpf(g[j + 2] - g[j]);
    invdd2[j] = __builtin_amdgcn_rcpf(g[j + 3] - g[j + 1]);
  }
#pragma unroll
  for (int j = 0; j < 8; ++j) {
    invdr3[j] = __builtin_amdgcn_rcpf(g[j + 3] - g[j]);
    invdd3[j] = __builtin_amdgcn_rcpf(g[j + 4] - g[j + 1]);
  }

  for (int bb = 0; bb < 8; ++bb) {
    const int b = b0 + bb;
    const float xv = x[(size_t)b * NIN + i];
    const float ge = 0.5f * xv * (1.0f + erff(xv * 0.70710678118654752f));
    __hip_bfloat16* Arow = A + (size_t)b * KTOT;
    Arow[i] = __float2bfloat16(ge);

    float bas[11];
#pragma unroll
    for (int j = 0; j < 11; ++j)
      bas[j] = (xv >= g[j] && xv < g[j + 1]) ? 1.0f : 0.0f;
#pragma unroll
    for (int j = 0; j < 10; ++j)
      bas[j] = (xv - g[j]) * invdr1[j] * bas[j] + (g[j + 2] - xv) * invdd1[j] * bas[j + 1];
#pragma unroll
    for (int j = 0; j < 9; ++j)
      bas[j] = (xv - g[j]) * invdr2[j] * bas[j] + (g[j + 3] - xv) * invdd2[j] * bas[j + 1];
#pragma unroll
    for (int j = 0; j < 8; ++j)
      bas[j] = (xv - g[j]) * invdr3[j] * bas[j] + (g[j + 4] - xv) * invdd3[j] * bas[j + 1];

    union { __hip_bfloat16 h[8]; uint4 v; } u;
#pragma unroll
    for (int k = 0; k < 8; ++k) u.h[k] = __float2bfloat16(bas[k]);
    *reinterpret_cast<uint4*>(Arow + NIN + i * 8) = u.v;
  }
}

// ---------------------------------------------------------------------------
// Kernel 2: W[o, 0:1024] = base_weight[o,:] ; W[o, 1024:] = spline_weight[o,:,:]
// ---------------------------------------------------------------------------
__global__ void convert_W(const float* __restrict__ bw,
                          const float* __restrict__ sw,
                          __hip_bfloat16* __restrict__ W) {
  const int idx = blockIdx.x * blockDim.x + threadIdx.x;
  const int o  = idx / 1152;
  const int c8 = (idx - o * 1152) * 8;
  const float* src = (c8 < 1024) ? (bw + (size_t)o * 1024 + c8)
                                 : (sw + (size_t)o * 8192 + (c8 - 1024));
  float4 f0 = reinterpret_cast<const float4*>(src)[0];
  float4 f1 = reinterpret_cast<const float4*>(src)[1];
  union { __hip_bfloat16 h[8]; uint4 v; } u;
  u.h[0] = __float2bfloat16(f0.x); u.h[1] = __float2bfloat16(f0.y);
  u.h[2] = __float2bfloat16(f0.z); u.h[3] = __float2bfloat16(f0.w);
  u.h[4] = __float2bfloat16(f1.x); u.h[5] = __float2bfloat16(f1.y);
  u.h[6] = __float2bfloat16(f1.z); u.h[7] = __float2bfloat16(f1.w);
  *reinterpret_cast<uint4*>(W + (size_t)o * KTOT + c8) = u.v;
}

// ---------------------------------------------------------------------------
// Kernel 3: 8-phase pipelined GEMM (T2+T3+T4+T5). 256x256 tile, BK=64,
// split-K=2, 8 waves (2M x 4N), per-wave 128x64 (acc[8][4]).
// LDS: 8 half-slots [buf][A0,A1,B0,B1][128][64] bf16 = 128 KB, XOR-swizzled
// (slot ^= row&7, 16B slots) via pre-swizzled global source + swizzled reads.
// Stage stream: 1 half/phase, in-order, lead 6 halves; vmcnt(6) every phase
// guarantees halves staged >=3 phases ago have landed (tail: 2 -> 0).
// Phases per K-tile: P1{rdA0,rdB0,stB0',vm,bar,mfma q00,bar}
//                    P2{rdB1,stB1',vm,bar,q01,bar}
//                    P3{rdA1,stA0'',vm,bar,q11,bar}
//                    P4{stA1'',vm,bar,q10,bar}   (' = t+1, '' = t+2)
// ---------------------------------------------------------------------------
__global__ __launch_bounds__(512, 2)
void gemm_8ph(const __hip_bfloat16* __restrict__ A,
              const __hip_bfloat16* __restrict__ Bw,
              float* __restrict__ P0,
              float* __restrict__ P1w) {
  __shared__ char smem[131072];   // [2][4][128][64] bf16 half-slots

  const int tid  = threadIdx.x;
  const int lane = tid & 63;
  const int wave = tid >> 6;
  const int wr = wave >> 2;          // 0..1 -> M half (128 rows)
  const int wc = wave & 3;           // 0..3 -> N quarter (64 cols)

  const int orig = blockIdx.x;                    // 256 blocks
  const int bid  = (orig & 7) * 32 + (orig >> 3); // bijective XCD chunking
  const int ks    = bid & 1;                      // K slice
  const int tileN = (bid >> 1) & 3;               // 4 N tiles
  const int tileM = bid >> 3;                     // 32 M tiles
  const size_t brow = (size_t)tileM * 256;
  const size_t bcol = (size_t)tileN * 256;
  const int kbeg = ks * KHALF;

  const __hip_bfloat16* Ab = A  + brow * KTOT;
  const __hip_bfloat16* Bb = Bw + bcol * KTOT;
  float* C = ks ? P1w : P0;

  // ---- staging (pre-swizzled global source, linear LDS dest) ----
  // thread tid -> half-row (tid>>3), phys 16B slot (tid&7); logical slot =
  // (tid&7) ^ ((tid>>3)&7). j=1 covers rows 64..127 (row&7 unchanged).
  const int swsrc = ((tid & 7) ^ ((tid >> 3) & 7)) * 8;
  const __hip_bfloat16* srcA = Ab + (size_t)(tid >> 3) * KTOT + kbeg + swsrc;
  const __hip_bfloat16* srcB = Bb + (size_t)(tid >> 3) * KTOT + kbeg + swsrc;
  const int wdst = wave * 1024;                  // wave-uniform LDS dest base

  auto stageA = [&](int bf, int h, int kt) {
    const __hip_bfloat16* g = srcA + (size_t)h * (128 * KTOT) + (size_t)kt * 64;
    char* d = smem + (bf * 4 + h) * 16384 + wdst;
    load_lds16(g, d);
    load_lds16(g + (size_t)64 * KTOT, d + 8192);
  };
  auto stageB = [&](int bf, int h, int kt) {
    const __hip_bfloat16* g = srcB + (size_t)h * (128 * KTOT) + (size_t)kt * 64;
    char* d = smem + (bf * 4 + 2 + h) * 16384 + wdst;
    load_lds16(g, d);
    load_lds16(g + (size_t)64 * KTOT, d + 8192);
  };

  // ---- fragment read addressing (XOR term is a per-lane constant) ----
  const int fr = lane & 15;
  const int hi = lane >> 4;                      // 0..3 -> k-slot within 32
  const int sw = (fr & 7) << 4;
  const int ax0 = (hi * 16) ^ sw;                // kk=0 slot byte
  const int ax1 = (64 + hi * 16) ^ sw;           // kk=1 slot byte

  bf16x8 a[4][2], b[4][2];
  f32x4 acc[8][4] = {};

#define RD_A(CB, MH) { \
    const char* Ah = smem + ((CB) * 4 + wr) * 16384 + (MH) * 64 * 128; \
    _Pragma("unroll") \
    for (int mi2 = 0; mi2 < 4; ++mi2) { \
      const char* p = Ah + (mi2 * 16 + fr) * 128; \
      a[mi2][0] = *(const bf16x8*)(p + ax0); \
      a[mi2][1] = *(const bf16x8*)(p + ax1); } }

#define RD_B(CB, NH) { \
    const char* Bh = smem + ((CB) * 4 + 2 + (wc >> 1)) * 16384 + ((wc & 1) * 64 + (NH) * 32) * 128; \
    _Pragma("unroll") \
    for (int ni2 = 0; ni2 < 2; ++ni2) { \
      const char* p = Bh + (ni2 * 16 + fr) * 128; \
      b[(NH) * 2 + ni2][0] = *(const bf16x8*)(p + ax0); \
      b[(NH) * 2 + ni2][1] = *(const bf16x8*)(p + ax1); } }

#define PHASE_BAR() do { asm volatile("" ::: "memory"); \
    __builtin_amdgcn_s_barrier(); \
    asm volatile("" ::: "memory"); } while (0)

#define QMFMA(MH, NH) do { \
    __builtin_amdgcn_s_setprio(1); \
    _Pragma("unroll") \
    for (int mi2 = 0; mi2 < 4; ++mi2) \
      _Pragma("unroll") \
      for (int ni2 = 0; ni2 < 2; ++ni2) \
        _Pragma("unroll") \
        for (int kk = 0; kk < 2; ++kk) \
          acc[(MH) * 4 + mi2][(NH) * 2 + ni2] = \
            __builtin_amdgcn_mfma_f32_16x16x32_bf16(a[mi2][kk], b[(NH) * 2 + ni2][kk], \
                                                    acc[(MH) * 4 + mi2][(NH) * 2 + ni2], 0, 0, 0); \
    __builtin_amdgcn_s_setprio(0); } while (0)

#define TILE(T, CB, STB, STA, VM3, VM4) do { \
    /* P1 */ \
    RD_A(CB, 0); RD_B(CB, 0); \
    if (STB) stageB((CB) ^ 1, 0, (T) + 1); \
    asm volatile("s_waitcnt vmcnt(6)" ::: "memory"); \
    PHASE_BAR(); QMFMA(0, 0); PHASE_BAR(); \
    /* P2 */ \
    RD_B(CB, 1); \
    if (STB) stageB((CB) ^ 1, 1, (T) + 1); \
    asm volatile("s_waitcnt vmcnt(6)" ::: "memory"); \
    PHASE_BAR(); QMFMA(0, 1); PHASE_BAR(); \
    /* P3 */ \
    RD_A(CB, 1); \
    if (STA) stageA(CB, 0, (T) + 2); \
    asm volatile(VM3 ::: "memory"); \
    PHASE_BAR(); QMFMA(1, 1); PHASE_BAR(); \
    /* P4 */ \
    if (STA) stageA(CB, 1, (T) + 2); \
    asm volatile(VM4 ::: "memory"); \
    PHASE_BAR(); QMFMA(1, 0); PHASE_BAR(); \
  } while (0)

  // prologue: stream halves n0..n5 = t0{A0,A1,B0,B1}, t1{A0,A1} (12 loads);
  // vmcnt(6) -> t0 complete.
  stageA(0, 0, 0); stageA(0, 1, 0); stageB(0, 0, 0); stageB(0, 1, 0);
  stageA(1, 0, 1); stageA(1, 1, 1);
  asm volatile("s_waitcnt vmcnt(6)" ::: "memory");
  PHASE_BAR();

  // main: t = 0..69 fully staged, vmcnt(6) throughout
  for (int it = 0; it < 35; ++it) {
    const int t0 = it * 2;
    TILE(t0, 0, 1, 1, "s_waitcnt vmcnt(6)", "s_waitcnt vmcnt(6)");
    TILE(t0 + 1, 1, 1, 1, "s_waitcnt vmcnt(6)", "s_waitcnt vmcnt(6)");
  }
  // t = 70: stages B(71) only; tail drains 2 -> 0
  TILE(70, 0, 1, 0, "s_waitcnt vmcnt(2)", "s_waitcnt vmcnt(0)");
  // t = 71: no stages, everything resident
  TILE(71, 1, 0, 0, "s_nop 0", "s_nop 0");

#undef TILE
#undef QMFMA
#undef PHASE_BAR
#undef RD_B
#undef RD_A

  // epilogue: C/D layout col = lane&15, row = (lane>>4)*4 + reg
  const int crow0 = (lane >> 4) * 4;
#pragma unroll
  for (int mi = 0; mi < 8; ++mi)
#pragma unroll
    for (int ni = 0; ni < 4; ++ni) {
      const size_t r0 = brow + wr * 128 + mi * 16 + crow0;
      const size_t cc = bcol + wc * 64 + ni * 16 + fr;
      float* cp = C + r0 * NOUT + cc;
#pragma unroll
      for (int r = 0; r < 4; ++r) cp[(size_t)r * NOUT] = acc[mi][ni][r];
    }
}

// ---------------------------------------------------------------------------
// Kernel 4: y = P0 + P1 (split-K reduce), rowwise LayerNorm + PReLU -> y.
// P1 aliases d_out. One block per row.
// ---------------------------------------------------------------------------
__global__ void reduce_ln_prelu(const float* __restrict__ P0,
                                float* __restrict__ y,
                                const float* __restrict__ gamma,
                                const float* __restrict__ beta,
                                const float* __restrict__ pa) {
  const int row = blockIdx.x;
  const int t = threadIdx.x;                 // 256 threads, 4 floats each
  const float* p0r = P0 + (size_t)row * NOUT;
  float* yr = y + (size_t)row * NOUT;

  float4 aa = reinterpret_cast<const float4*>(p0r)[t];
  float4 v = reinterpret_cast<const float4*>(yr)[t];
  v.x += aa.x; v.y += aa.y; v.z += aa.z; v.w += aa.w;

  float s  = v.x + v.y + v.z + v.w;
  float sq = v.x * v.x + v.y * v.y + v.z * v.z + v.w * v.w;
#pragma unroll
  for (int off = 32; off > 0; off >>= 1) {
    s  += __shfl_down(s, off);
    sq += __shfl_down(sq, off);
  }
  __shared__ float red[8];
  const int wv = t >> 6, lane = t & 63;
  if (lane == 0) { red[wv] = s; red[4 + wv] = sq; }
  __syncthreads();
  if (t == 0) {
    const float S = red[0] + red[1] + red[2] + red[3];
    const float Q = red[4] + red[5] + red[6] + red[7];
    const float mu = S * (1.0f / NOUT);
    const float var = Q * (1.0f / NOUT) - mu * mu;
    red[0] = mu;
    red[1] = rsqrtf(var + 1e-5f);
  }
  __syncthreads();
  const float mu = red[0], rs = red[1];
  const float aP = pa[0];
  const float4 g4 = reinterpret_cast<const float4*>(gamma)[t];
  const float4 b4 = reinterpret_cast<const float4*>(beta)[t];
  float o0 = (v.x - mu) * rs * g4.x + b4.x;
  float o1 = (v.y - mu) * rs * g4.y + b4.y;
  float o2 = (v.z - mu) * rs * g4.z + b4.z;
  float o3 = (v.w - mu) * rs * g4.w + b4.w;
  v.x = o0 >= 0.0f ? o0 : aP * o0;
  v.y = o1 >= 0.0f ? o1 : aP * o1;
  v.z = o2 >= 0.0f ? o2 : aP * o2;
  v.w = o3 >= 0.0f ? o3 : aP * o3;
  reinterpret_cast<float4*>(yr)[t] = v;
}

// ---------------------------------------------------------------------------
extern "C" void kernel_launch(void* const* d_in, const int* in_sizes, int n_in,
                              void* d_out, int out_size, void* d_ws, size_t ws_size,
                              hipStream_t stream) {
  const float* x     = (const float*)d_in[0];
  const float* bw    = (const float*)d_in[1];
  const float* sw    = (const float*)d_in[2];
  const float* grid  = (const float*)d_in[3];
  const float* gamma = (const float*)d_in[4];
  const float* beta  = (const float*)d_in[5];
  const float* pa    = (const float*)d_in[6];
  float* out = (float*)d_out;

  __hip_bfloat16* Abuf = (__hip_bfloat16*)d_ws;                 // 8192 x 9216 bf16
  __hip_bfloat16* Wbuf = Abuf + (size_t)NB * KTOT;              // 1024 x 9216 bf16
  float* P0 = (float*)(Wbuf + (size_t)NOUT * KTOT);             // 8192 x 1024 f32

  build_A<<<(NB / 8) * NIN / 256, 256, 0, stream>>>(x, grid, Abuf);
  convert_W<<<NOUT * (KTOT / 8) / 256, 256, 0, stream>>>(bw, sw, Wbuf);
  gemm_8ph<<<(NB / 256) * (NOUT / 256) * 2, 512, 0, stream>>>(Abuf, Wbuf, P0, out);
  reduce_ln_prelu<<<NB, 256, 0, stream>>>(P0, out, gamma, beta, pa);
}

// Round 7
// 204.457 us; speedup vs baseline: 1.4384x; 1.0244x over previous
//
#include <hip/hip_runtime.h>
#include <hip/hip_bf16.h>

typedef __attribute__((ext_vector_type(8))) short bf16x8;   // 8 bf16 (4 VGPRs)
typedef __attribute__((ext_vector_type(4))) float f32x4;    // MFMA C/D

#define KTOT 9216   // 1024 (gelu part) + 1024*8 (spline bases part)
#define KHALF 4608  // split-K slice
#define NB   8192
#define NIN  1024
#define NOUT 1024

__device__ __forceinline__ void load_lds16(const void* g, void* l) {
  __builtin_amdgcn_global_load_lds(
      (const __attribute__((address_space(1))) void*)g,
      (__attribute__((address_space(3))) void*)l, 16, 0, 0);
}

// ---------------------------------------------------------------------------
// Kernel 1 (merged prep): blocks [0,4096) build A; blocks [4096,8704) pack W.
// ---------------------------------------------------------------------------
__global__ void prep(const float* __restrict__ x,
                     const float* __restrict__ grid,
                     __hip_bfloat16* __restrict__ A,
                     const float* __restrict__ bw,
                     const float* __restrict__ sw,
                     __hip_bfloat16* __restrict__ W) {
  if (blockIdx.x < 4096) {
    const int tid = blockIdx.x * blockDim.x + threadIdx.x;
    const int i  = tid & (NIN - 1);
    const int b0 = (tid >> 10) << 3;                       // 8 rows / thread

    float g[12];
#pragma unroll
    for (int j = 0; j < 12; ++j) g[j] = grid[j];

    float invdr1[10], invdd1[10], invdr2[9], invdd2[9], invdr3[8], invdd3[8];
#pragma unroll
    for (int j = 0; j < 10; ++j) {
      invdr1[j] = __builtin_amdgcn_rcpf(g[j + 1] - g[j]);
      invdd1[j] = __builtin_amdgcn_rcpf(g[j + 2] - g[j + 1]);
    }
#pragma unroll
    for (int j = 0; j < 9; ++j) {
      invdr2[j] = __builtin_amdgcn_rcpf(g[j + 2] - g[j]);
      invdd2[j] = __builtin_amdgcn_rcpf(g[j + 3] - g[j + 1]);
    }
#pragma unroll
    for (int j = 0; j < 8; ++j) {
      invdr3[j] = __builtin_amdgcn_rcpf(g[j + 3] - g[j]);
      invdd3[j] = __builtin_amdgcn_rcpf(g[j + 4] - g[j + 1]);
    }

    for (int bb = 0; bb < 8; ++bb) {
      const int b = b0 + bb;
      const float xv = x[(size_t)b * NIN + i];
      const float ge = 0.5f * xv * (1.0f + erff(xv * 0.70710678118654752f));
      __hip_bfloat16* Arow = A + (size_t)b * KTOT;
      Arow[i] = __float2bfloat16(ge);

      float bas[11];
#pragma unroll
      for (int j = 0; j < 11; ++j)
        bas[j] = (xv >= g[j] && xv < g[j + 1]) ? 1.0f : 0.0f;
#pragma unroll
      for (int j = 0; j < 10; ++j)
        bas[j] = (xv - g[j]) * invdr1[j] * bas[j] + (g[j + 2] - xv) * invdd1[j] * bas[j + 1];
#pragma unroll
      for (int j = 0; j < 9; ++j)
        bas[j] = (xv - g[j]) * invdr2[j] * bas[j] + (g[j + 3] - xv) * invdd2[j] * bas[j + 1];
#pragma unroll
      for (int j = 0; j < 8; ++j)
        bas[j] = (xv - g[j]) * invdr3[j] * bas[j] + (g[j + 4] - xv) * invdd3[j] * bas[j + 1];

      union { __hip_bfloat16 h[8]; uint4 v; } u;
#pragma unroll
      for (int k = 0; k < 8; ++k) u.h[k] = __float2bfloat16(bas[k]);
      *reinterpret_cast<uint4*>(Arow + NIN + i * 8) = u.v;
    }
  } else {
    const int idx = (blockIdx.x - 4096) * blockDim.x + threadIdx.x;
    const int o  = idx / 1152;
    const int c8 = (idx - o * 1152) * 8;
    const float* src = (c8 < 1024) ? (bw + (size_t)o * 1024 + c8)
                                   : (sw + (size_t)o * 8192 + (c8 - 1024));
    float4 f0 = reinterpret_cast<const float4*>(src)[0];
    float4 f1 = reinterpret_cast<const float4*>(src)[1];
    union { __hip_bfloat16 h[8]; uint4 v; } u;
    u.h[0] = __float2bfloat16(f0.x); u.h[1] = __float2bfloat16(f0.y);
    u.h[2] = __float2bfloat16(f0.z); u.h[3] = __float2bfloat16(f0.w);
    u.h[4] = __float2bfloat16(f1.x); u.h[5] = __float2bfloat16(f1.y);
    u.h[6] = __float2bfloat16(f1.z); u.h[7] = __float2bfloat16(f1.w);
    *reinterpret_cast<uint4*>(W + (size_t)o * KTOT + c8) = u.v;
  }
}

// ---------------------------------------------------------------------------
// Kernel 2: 8-phase pipelined GEMM (T2+T3+T4+T5) — R5-verified 16x16x32 form.
// 256x256 tile, BK=64, split-K=2, 8 waves (2M x 4N), per-wave 128x64.
// vmcnt schedule: P1/P2/P4 = vmcnt(6); P3 has none (it would gate only P4,
// which reads nothing). Tail: tile70 = (6,6,-,2), tile71 = (0,-,-,-).
// ---------------------------------------------------------------------------
__global__ __launch_bounds__(512, 2)
void gemm_8ph(const __hip_bfloat16* __restrict__ A,
              const __hip_bfloat16* __restrict__ Bw,
              float* __restrict__ P0,
              float* __restrict__ P1w) {
  __shared__ char smem[131072];   // [2][A0,A1,B0,B1][128 rows][128 B]

  const int tid  = threadIdx.x;
  const int lane = tid & 63;
  const int wave = tid >> 6;
  const int wr = wave >> 2;          // 0..1 -> M half (128 rows)
  const int wc = wave & 3;           // 0..3 -> N quarter (64 cols)

  const int orig = blockIdx.x;                    // 256 blocks
  const int bid  = (orig & 7) * 32 + (orig >> 3); // bijective XCD chunking
  const int ks    = bid & 1;                      // K slice
  const int tileN = (bid >> 1) & 3;               // 4 N tiles
  const int tileM = bid >> 3;                     // 32 M tiles
  const size_t brow = (size_t)tileM * 256;
  const size_t bcol = (size_t)tileN * 256;
  const int kbeg = ks * KHALF;

  const __hip_bfloat16* Ab = A  + brow * KTOT;
  const __hip_bfloat16* Bb = Bw + bcol * KTOT;
  float* C = ks ? P1w : P0;

  // ---- staging (pre-swizzled global source, linear LDS dest) ----
  const int swsrc = ((tid & 7) ^ ((tid >> 3) & 7)) * 8;
  const __hip_bfloat16* srcA = Ab + (size_t)(tid >> 3) * KTOT + kbeg + swsrc;
  const __hip_bfloat16* srcB = Bb + (size_t)(tid >> 3) * KTOT + kbeg + swsrc;
  const int wdst = wave * 1024;

  auto stageA = [&](int bf, int h, int kt) {
    const __hip_bfloat16* g = srcA + (size_t)h * (128 * KTOT) + (size_t)kt * 64;
    char* d = smem + (bf * 4 + h) * 16384 + wdst;
    load_lds16(g, d);
    load_lds16(g + (size_t)64 * KTOT, d + 8192);
  };
  auto stageB = [&](int bf, int h, int kt) {
    const __hip_bfloat16* g = srcB + (size_t)h * (128 * KTOT) + (size_t)kt * 64;
    char* d = smem + (bf * 4 + 2 + h) * 16384 + wdst;
    load_lds16(g, d);
    load_lds16(g + (size_t)64 * KTOT, d + 8192);
  };

  // ---- fragment read addressing (XOR term is a per-lane constant) ----
  const int fr = lane & 15;
  const int hi = lane >> 4;                      // 0..3 -> k-slot within 32
  const int sw = (fr & 7) << 4;
  const int ax0 = (hi * 16) ^ sw;                // kk=0 slot byte
  const int ax1 = (64 + hi * 16) ^ sw;           // kk=1 slot byte

  bf16x8 a[4][2], b[4][2];
  f32x4 acc[8][4] = {};

#define RD_A(CB, MH) { \
    const char* Ah = smem + ((CB) * 4 + wr) * 16384 + (MH) * 64 * 128; \
    _Pragma("unroll") \
    for (int mi2 = 0; mi2 < 4; ++mi2) { \
      const char* p = Ah + (mi2 * 16 + fr) * 128; \
      a[mi2][0] = *(const bf16x8*)(p + ax0); \
      a[mi2][1] = *(const bf16x8*)(p + ax1); } }

#define RD_B(CB, NH) { \
    const char* Bh = smem + ((CB) * 4 + 2 + (wc >> 1)) * 16384 + ((wc & 1) * 64 + (NH) * 32) * 128; \
    _Pragma("unroll") \
    for (int ni2 = 0; ni2 < 2; ++ni2) { \
      const char* p = Bh + (ni2 * 16 + fr) * 128; \
      b[(NH) * 2 + ni2][0] = *(const bf16x8*)(p + ax0); \
      b[(NH) * 2 + ni2][1] = *(const bf16x8*)(p + ax1); } }

#define PHASE_BAR() do { asm volatile("" ::: "memory"); \
    __builtin_amdgcn_s_barrier(); \
    asm volatile("" ::: "memory"); } while (0)

#define QMFMA(MH, NH) do { \
    __builtin_amdgcn_s_setprio(1); \
    _Pragma("unroll") \
    for (int mi2 = 0; mi2 < 4; ++mi2) \
      _Pragma("unroll") \
      for (int ni2 = 0; ni2 < 2; ++ni2) \
        _Pragma("unroll") \
        for (int kk = 0; kk < 2; ++kk) \
          acc[(MH) * 4 + mi2][(NH) * 2 + ni2] = \
            __builtin_amdgcn_mfma_f32_16x16x32_bf16(a[mi2][kk], b[(NH) * 2 + ni2][kk], \
                                                    acc[(MH) * 4 + mi2][(NH) * 2 + ni2], 0, 0, 0); \
    __builtin_amdgcn_s_setprio(0); } while (0)

#define TILE(T, CB, STB, STA, VM1, VM2, VM4) do { \
    /* P1 */ \
    RD_A(CB, 0); RD_B(CB, 0); \
    if (STB) stageB((CB) ^ 1, 0, (T) + 1); \
    asm volatile(VM1 ::: "memory"); \
    PHASE_BAR(); QMFMA(0, 0); PHASE_BAR(); \
    /* P2 */ \
    RD_B(CB, 1); \
    if (STB) stageB((CB) ^ 1, 1, (T) + 1); \
    asm volatile(VM2 ::: "memory"); \
    PHASE_BAR(); QMFMA(0, 1); PHASE_BAR(); \
    /* P3 (no vmcnt: it would gate only P4, which reads nothing) */ \
    RD_A(CB, 1); \
    if (STA) stageA(CB, 0, (T) + 2); \
    PHASE_BAR(); QMFMA(1, 1); PHASE_BAR(); \
    /* P4 (vmcnt gates next tile's P1 reads) */ \
    if (STA) stageA(CB, 1, (T) + 2); \
    asm volatile(VM4 ::: "memory"); \
    PHASE_BAR(); QMFMA(1, 0); PHASE_BAR(); \
  } while (0)

  // prologue: halves t0{A0,A1,B0,B1}, t1{A0,A1} (12 loads); vmcnt(6) -> t0 done
  stageA(0, 0, 0); stageA(0, 1, 0); stageB(0, 0, 0); stageB(0, 1, 0);
  stageA(1, 0, 1); stageA(1, 1, 1);
  asm volatile("s_waitcnt vmcnt(6)" ::: "memory");
  PHASE_BAR();

  // main: t = 0..69 fully staged
  for (int it = 0; it < 35; ++it) {
    const int t0 = it * 2;
    TILE(t0, 0, 1, 1,
         "s_waitcnt vmcnt(6)", "s_waitcnt vmcnt(6)", "s_waitcnt vmcnt(6)");
    TILE(t0 + 1, 1, 1, 1,
         "s_waitcnt vmcnt(6)", "s_waitcnt vmcnt(6)", "s_waitcnt vmcnt(6)");
  }
  // t = 70: stages B(71) only; P4 drains to 2 (leaves B1(71) in flight)
  TILE(70, 0, 1, 0,
       "s_waitcnt vmcnt(6)", "s_waitcnt vmcnt(6)", "s_waitcnt vmcnt(2)");
  // t = 71: no stages; P1 drains to 0 before P2 reads B1(71)
  TILE(71, 1, 0, 0,
       "s_waitcnt vmcnt(0)", "s_nop 0", "s_nop 0");

#undef TILE
#undef QMFMA
#undef PHASE_BAR
#undef RD_B
#undef RD_A

  // epilogue: C/D layout col = lane&15, row = (lane>>4)*4 + reg
  const int crow0 = (lane >> 4) * 4;
#pragma unroll
  for (int mi = 0; mi < 8; ++mi)
#pragma unroll
    for (int ni = 0; ni < 4; ++ni) {
      const size_t r0 = brow + wr * 128 + mi * 16 + crow0;
      const size_t cc = bcol + wc * 64 + ni * 16 + fr;
      float* cp = C + r0 * NOUT + cc;
#pragma unroll
      for (int r = 0; r < 4; ++r) cp[(size_t)r * NOUT] = acc[mi][ni][r];
    }
}

// ---------------------------------------------------------------------------
// Kernel 3: y = P0 + P1 (split-K reduce), rowwise LayerNorm + PReLU -> y.
// P1 aliases d_out. One block per row.
// ---------------------------------------------------------------------------
__global__ void reduce_ln_prelu(const float* __restrict__ P0,
                                float* __restrict__ y,
                                const float* __restrict__ gamma,
                                const float* __restrict__ beta,
                                const float* __restrict__ pa) {
  const int row = blockIdx.x;
  const int t = threadIdx.x;                 // 256 threads, 4 floats each
  const float* p0r = P0 + (size_t)row * NOUT;
  float* yr = y + (size_t)row * NOUT;

  float4 aa = reinterpret_cast<const float4*>(p0r)[t];
  float4 v = reinterpret_cast<const float4*>(yr)[t];
  v.x += aa.x; v.y += aa.y; v.z += aa.z; v.w += aa.w;

  float s  = v.x + v.y + v.z + v.w;
  float sq = v.x * v.x + v.y * v.y + v.z * v.z + v.w * v.w;
#pragma unroll
  for (int off = 32; off > 0; off >>= 1) {
    s  += __shfl_down(s, off);
    sq += __shfl_down(sq, off);
  }
  __shared__ float red[8];
  const int wv = t >> 6, lane = t & 63;
  if (lane == 0) { red[wv] = s; red[4 + wv] = sq; }
  __syncthreads();
  if (t == 0) {
    const float S = red[0] + red[1] + red[2] + red[3];
    const float Q = red[4] + red[5] + red[6] + red[7];
    const float mu = S * (1.0f / NOUT);
    const float var = Q * (1.0f / NOUT) - mu * mu;
    red[0] = mu;
    red[1] = rsqrtf(var + 1e-5f);
  }
  __syncthreads();
  const float mu = red[0], rs = red[1];
  const float aP = pa[0];
  const float4 g4 = reinterpret_cast<const float4*>(gamma)[t];
  const float4 b4 = reinterpret_cast<const float4*>(beta)[t];
  float o0 = (v.x - mu) * rs * g4.x + b4.x;
  float o1 = (v.y - mu) * rs * g4.y + b4.y;
  float o2 = (v.z - mu) * rs * g4.z + b4.z;
  float o3 = (v.w - mu) * rs * g4.w + b4.w;
  v.x = o0 >= 0.0f ? o0 : aP * o0;
  v.y = o1 >= 0.0f ? o1 : aP * o1;
  v.z = o2 >= 0.0f ? o2 : aP * o2;
  v.w = o3 >= 0.0f ? o3 : aP * o3;
  reinterpret_cast<float4*>(yr)[t] = v;
}

// ---------------------------------------------------------------------------
extern "C" void kernel_launch(void* const* d_in, const int* in_sizes, int n_in,
                              void* d_out, int out_size, void* d_ws, size_t ws_size,
                              hipStream_t stream) {
  const float* x     = (const float*)d_in[0];
  const float* bw    = (const float*)d_in[1];
  const float* sw    = (const float*)d_in[2];
  const float* grid  = (const float*)d_in[3];
  const float* gamma = (const float*)d_in[4];
  const float* beta  = (const float*)d_in[5];
  const float* pa    = (const float*)d_in[6];
  float* out = (float*)d_out;

  __hip_bfloat16* Abuf = (__hip_bfloat16*)d_ws;                 // 8192 x 9216 bf16
  __hip_bfloat16* Wbuf = Abuf + (size_t)NB * KTOT;              // 1024 x 9216 bf16
  float* P0 = (float*)(Wbuf + (size_t)NOUT * KTOT);             // 8192 x 1024 f32

  prep<<<4096 + 4608, 256, 0, stream>>>(x, grid, Abuf, bw, sw, Wbuf);
  gemm_8ph<<<(NB / 256) * (NOUT / 256) * 2, 512, 0, stream>>>(Abuf, Wbuf, P0, out);
  reduce_ln_prelu<<<NB, 256, 0, stream>>>(P0, out, gamma, beta, pa);
}

// Round 8
// 202.428 us; speedup vs baseline: 1.4528x; 1.0100x over previous
//
#include <hip/hip_runtime.h>
#include <hip/hip_bf16.h>

typedef __attribute__((ext_vector_type(8))) short bf16x8;   // 8 bf16 (4 VGPRs)
typedef __attribute__((ext_vector_type(4))) float f32x4;    // MFMA C/D

#define KTOT 9216   // 1024 (gelu part) + 1024*8 (spline bases part)
#define KHALF 4608  // split-K slice
#define NB   8192
#define NIN  1024
#define NOUT 1024

__device__ __forceinline__ void load_lds16(const void* g, void* l) {
  __builtin_amdgcn_global_load_lds(
      (const __attribute__((address_space(1))) void*)g,
      (__attribute__((address_space(3))) void*)l, 16, 0, 0);
}

// ---------------------------------------------------------------------------
// Kernel 1 (merged prep): blocks [0,4096) build A; blocks [4096,8704) pack W.
// ---------------------------------------------------------------------------
__global__ void prep(const float* __restrict__ x,
                     const float* __restrict__ grid,
                     __hip_bfloat16* __restrict__ A,
                     const float* __restrict__ bw,
                     const float* __restrict__ sw,
                     __hip_bfloat16* __restrict__ W) {
  if (blockIdx.x < 4096) {
    const int tid = blockIdx.x * blockDim.x + threadIdx.x;
    const int i  = tid & (NIN - 1);
    const int b0 = (tid >> 10) << 3;                       // 8 rows / thread

    float g[12];
#pragma unroll
    for (int j = 0; j < 12; ++j) g[j] = grid[j];

    float invdr1[10], invdd1[10], invdr2[9], invdd2[9], invdr3[8], invdd3[8];
#pragma unroll
    for (int j = 0; j < 10; ++j) {
      invdr1[j] = __builtin_amdgcn_rcpf(g[j + 1] - g[j]);
      invdd1[j] = __builtin_amdgcn_rcpf(g[j + 2] - g[j + 1]);
    }
#pragma unroll
    for (int j = 0; j < 9; ++j) {
      invdr2[j] = __builtin_amdgcn_rcpf(g[j + 2] - g[j]);
      invdd2[j] = __builtin_amdgcn_rcpf(g[j + 3] - g[j + 1]);
    }
#pragma unroll
    for (int j = 0; j < 8; ++j) {
      invdr3[j] = __builtin_amdgcn_rcpf(g[j + 3] - g[j]);
      invdd3[j] = __builtin_amdgcn_rcpf(g[j + 4] - g[j + 1]);
    }

    for (int bb = 0; bb < 8; ++bb) {
      const int b = b0 + bb;
      const float xv = x[(size_t)b * NIN + i];
      const float ge = 0.5f * xv * (1.0f + erff(xv * 0.70710678118654752f));
      __hip_bfloat16* Arow = A + (size_t)b * KTOT;
      Arow[i] = __float2bfloat16(ge);

      float bas[11];
#pragma unroll
      for (int j = 0; j < 11; ++j)
        bas[j] = (xv >= g[j] && xv < g[j + 1]) ? 1.0f : 0.0f;
#pragma unroll
      for (int j = 0; j < 10; ++j)
        bas[j] = (xv - g[j]) * invdr1[j] * bas[j] + (g[j + 2] - xv) * invdd1[j] * bas[j + 1];
#pragma unroll
      for (int j = 0; j < 9; ++j)
        bas[j] = (xv - g[j]) * invdr2[j] * bas[j] + (g[j + 3] - xv) * invdd2[j] * bas[j + 1];
#pragma unroll
      for (int j = 0; j < 8; ++j)
        bas[j] = (xv - g[j]) * invdr3[j] * bas[j] + (g[j + 4] - xv) * invdd3[j] * bas[j + 1];

      union { __hip_bfloat16 h[8]; uint4 v; } u;
#pragma unroll
      for (int k = 0; k < 8; ++k) u.h[k] = __float2bfloat16(bas[k]);
      *reinterpret_cast<uint4*>(Arow + NIN + i * 8) = u.v;
    }
  } else {
    const int idx = (blockIdx.x - 4096) * blockDim.x + threadIdx.x;
    const int o  = idx / 1152;
    const int c8 = (idx - o * 1152) * 8;
    const float* src = (c8 < 1024) ? (bw + (size_t)o * 1024 + c8)
                                   : (sw + (size_t)o * 8192 + (c8 - 1024));
    float4 f0 = reinterpret_cast<const float4*>(src)[0];
    float4 f1 = reinterpret_cast<const float4*>(src)[1];
    union { __hip_bfloat16 h[8]; uint4 v; } u;
    u.h[0] = __float2bfloat16(f0.x); u.h[1] = __float2bfloat16(f0.y);
    u.h[2] = __float2bfloat16(f0.z); u.h[3] = __float2bfloat16(f0.w);
    u.h[4] = __float2bfloat16(f1.x); u.h[5] = __float2bfloat16(f1.y);
    u.h[6] = __float2bfloat16(f1.z); u.h[7] = __float2bfloat16(f1.w);
    *reinterpret_cast<uint4*>(W + (size_t)o * KTOT + c8) = u.v;
  }
}

// ---------------------------------------------------------------------------
// Kernel 2: 8-phase pipelined GEMM (T2+T3+T4+T5), SINGLE-barrier phases.
// 256x256 tile, BK=64, split-K=2, 8 waves (2M x 4N), per-wave 128x64.
// Phase = {reads, stage, vmcnt, lgkmcnt(0), BAR, MFMA}. The lgkmcnt before
// the barrier guarantees every wave's reads are in registers before any wave
// passes the barrier and issues the next stage (overwrite-protection that the
// old post-MFMA barrier provided). Waves may drift: one wave's MFMA overlaps
// another's reads. vmcnt gating re-verified: P1/P2/P4 vmcnt(6); steady-state
// drains are exactly {B1(T)}, {A0(T+1)}, {A1(T+1),B0(T+1)} -> every half
// lands >= 1 barrier before its first read. Tail: t70 P4 = vmcnt(2),
// t71 P1 = vmcnt(0).
// ---------------------------------------------------------------------------
__global__ __launch_bounds__(512, 2)
void gemm_8ph(const __hip_bfloat16* __restrict__ A,
              const __hip_bfloat16* __restrict__ Bw,
              float* __restrict__ P0,
              float* __restrict__ P1w) {
  __shared__ char smem[131072];   // [2][A0,A1,B0,B1][128 rows][128 B]

  const int tid  = threadIdx.x;
  const int lane = tid & 63;
  const int wave = tid >> 6;
  const int wr = wave >> 2;          // 0..1 -> M half (128 rows)
  const int wc = wave & 3;           // 0..3 -> N quarter (64 cols)

  const int orig = blockIdx.x;                    // 256 blocks
  const int bid  = (orig & 7) * 32 + (orig >> 3); // bijective XCD chunking
  const int ks    = bid & 1;                      // K slice
  const int tileN = (bid >> 1) & 3;               // 4 N tiles
  const int tileM = bid >> 3;                     // 32 M tiles
  const size_t brow = (size_t)tileM * 256;
  const size_t bcol = (size_t)tileN * 256;
  const int kbeg = ks * KHALF;

  const __hip_bfloat16* Ab = A  + brow * KTOT;
  const __hip_bfloat16* Bb = Bw + bcol * KTOT;
  float* C = ks ? P1w : P0;

  // ---- staging (pre-swizzled global source, linear LDS dest) ----
  const int swsrc = ((tid & 7) ^ ((tid >> 3) & 7)) * 8;
  const __hip_bfloat16* srcA = Ab + (size_t)(tid >> 3) * KTOT + kbeg + swsrc;
  const __hip_bfloat16* srcB = Bb + (size_t)(tid >> 3) * KTOT + kbeg + swsrc;
  const int wdst = wave * 1024;

  auto stageA = [&](int bf, int h, int kt) {
    const __hip_bfloat16* g = srcA + (size_t)h * (128 * KTOT) + (size_t)kt * 64;
    char* d = smem + (bf * 4 + h) * 16384 + wdst;
    load_lds16(g, d);
    load_lds16(g + (size_t)64 * KTOT, d + 8192);
  };
  auto stageB = [&](int bf, int h, int kt) {
    const __hip_bfloat16* g = srcB + (size_t)h * (128 * KTOT) + (size_t)kt * 64;
    char* d = smem + (bf * 4 + 2 + h) * 16384 + wdst;
    load_lds16(g, d);
    load_lds16(g + (size_t)64 * KTOT, d + 8192);
  };

  // ---- fragment read addressing (XOR term is a per-lane constant) ----
  const int fr = lane & 15;
  const int hi = lane >> 4;                      // 0..3 -> k-slot within 32
  const int sw = (fr & 7) << 4;
  const int ax0 = (hi * 16) ^ sw;                // kk=0 slot byte
  const int ax1 = (64 + hi * 16) ^ sw;           // kk=1 slot byte

  bf16x8 a[4][2], b[4][2];
  f32x4 acc[8][4] = {};

#define RD_A(CB, MH) { \
    const char* Ah = smem + ((CB) * 4 + wr) * 16384 + (MH) * 64 * 128; \
    _Pragma("unroll") \
    for (int mi2 = 0; mi2 < 4; ++mi2) { \
      const char* p = Ah + (mi2 * 16 + fr) * 128; \
      a[mi2][0] = *(const bf16x8*)(p + ax0); \
      a[mi2][1] = *(const bf16x8*)(p + ax1); } }

#define RD_B(CB, NH) { \
    const char* Bh = smem + ((CB) * 4 + 2 + (wc >> 1)) * 16384 + ((wc & 1) * 64 + (NH) * 32) * 128; \
    _Pragma("unroll") \
    for (int ni2 = 0; ni2 < 2; ++ni2) { \
      const char* p = Bh + (ni2 * 16 + fr) * 128; \
      b[(NH) * 2 + ni2][0] = *(const bf16x8*)(p + ax0); \
      b[(NH) * 2 + ni2][1] = *(const bf16x8*)(p + ax1); } }

// single-barrier phase boundary: all our ds_reads are in regs, then barrier
#define SYNC1() do { \
    asm volatile("s_waitcnt lgkmcnt(0)" ::: "memory"); \
    __builtin_amdgcn_s_barrier(); \
    asm volatile("" ::: "memory"); } while (0)

#define QMFMA(MH, NH) do { \
    __builtin_amdgcn_s_setprio(1); \
    _Pragma("unroll") \
    for (int mi2 = 0; mi2 < 4; ++mi2) \
      _Pragma("unroll") \
      for (int ni2 = 0; ni2 < 2; ++ni2) \
        _Pragma("unroll") \
        for (int kk = 0; kk < 2; ++kk) \
          acc[(MH) * 4 + mi2][(NH) * 2 + ni2] = \
            __builtin_amdgcn_mfma_f32_16x16x32_bf16(a[mi2][kk], b[(NH) * 2 + ni2][kk], \
                                                    acc[(MH) * 4 + mi2][(NH) * 2 + ni2], 0, 0, 0); \
    __builtin_amdgcn_s_setprio(0); } while (0)

#define TILE(T, CB, STB, STA, VM1, VM2, VM4) do { \
    /* P1 */ \
    RD_A(CB, 0); RD_B(CB, 0); \
    if (STB) stageB((CB) ^ 1, 0, (T) + 1); \
    asm volatile(VM1 ::: "memory"); \
    SYNC1(); QMFMA(0, 0); \
    /* P2 */ \
    RD_B(CB, 1); \
    if (STB) stageB((CB) ^ 1, 1, (T) + 1); \
    asm volatile(VM2 ::: "memory"); \
    SYNC1(); QMFMA(0, 1); \
    /* P3 (no vmcnt needed) */ \
    RD_A(CB, 1); \
    if (STA) stageA(CB, 0, (T) + 2); \
    SYNC1(); QMFMA(1, 1); \
    /* P4 (vmcnt gates next tile's P1 reads) */ \
    if (STA) stageA(CB, 1, (T) + 2); \
    asm volatile(VM4 ::: "memory"); \
    SYNC1(); QMFMA(1, 0); \
  } while (0)

  // prologue: halves t0{A0,A1,B0,B1}, t1{A0,A1} (12 loads); vmcnt(6) -> t0 done
  stageA(0, 0, 0); stageA(0, 1, 0); stageB(0, 0, 0); stageB(0, 1, 0);
  stageA(1, 0, 1); stageA(1, 1, 1);
  asm volatile("s_waitcnt vmcnt(6)" ::: "memory");
  __builtin_amdgcn_s_barrier();
  asm volatile("" ::: "memory");

  // main: t = 0..69 fully staged
  for (int it = 0; it < 35; ++it) {
    const int t0 = it * 2;
    TILE(t0, 0, 1, 1,
         "s_waitcnt vmcnt(6)", "s_waitcnt vmcnt(6)", "s_waitcnt vmcnt(6)");
    TILE(t0 + 1, 1, 1, 1,
         "s_waitcnt vmcnt(6)", "s_waitcnt vmcnt(6)", "s_waitcnt vmcnt(6)");
  }
  // t = 70: stages B(71) only; P4 drains to 2 (leaves B1(71) in flight)
  TILE(70, 0, 1, 0,
       "s_waitcnt vmcnt(6)", "s_waitcnt vmcnt(6)", "s_waitcnt vmcnt(2)");
  // t = 71: no stages; P1 drains to 0 before P2 reads B1(71)
  TILE(71, 1, 0, 0,
       "s_waitcnt vmcnt(0)", "s_nop 0", "s_nop 0");

#undef TILE
#undef QMFMA
#undef SYNC1
#undef RD_B
#undef RD_A

  // epilogue: C/D layout col = lane&15, row = (lane>>4)*4 + reg
  const int crow0 = (lane >> 4) * 4;
#pragma unroll
  for (int mi = 0; mi < 8; ++mi)
#pragma unroll
    for (int ni = 0; ni < 4; ++ni) {
      const size_t r0 = brow + wr * 128 + mi * 16 + crow0;
      const size_t cc = bcol + wc * 64 + ni * 16 + fr;
      float* cp = C + r0 * NOUT + cc;
#pragma unroll
      for (int r = 0; r < 4; ++r) cp[(size_t)r * NOUT] = acc[mi][ni][r];
    }
}

// ---------------------------------------------------------------------------
// Kernel 3: y = P0 + P1 (split-K reduce), rowwise LayerNorm + PReLU -> y.
// P1 aliases d_out. One block per row.
// ---------------------------------------------------------------------------
__global__ void reduce_ln_prelu(const float* __restrict__ P0,
                                float* __restrict__ y,
                                const float* __restrict__ gamma,
                                const float* __restrict__ beta,
                                const float* __restrict__ pa) {
  const int row = blockIdx.x;
  const int t = threadIdx.x;                 // 256 threads, 4 floats each
  const float* p0r = P0 + (size_t)row * NOUT;
  float* yr = y + (size_t)row * NOUT;

  float4 aa = reinterpret_cast<const float4*>(p0r)[t];
  float4 v = reinterpret_cast<const float4*>(yr)[t];
  v.x += aa.x; v.y += aa.y; v.z += aa.z; v.w += aa.w;

  float s  = v.x + v.y + v.z + v.w;
  float sq = v.x * v.x + v.y * v.y + v.z * v.z + v.w * v.w;
#pragma unroll
  for (int off = 32; off > 0; off >>= 1) {
    s  += __shfl_down(s, off);
    sq += __shfl_down(sq, off);
  }
  __shared__ float red[8];
  const int wv = t >> 6, lane = t & 63;
  if (lane == 0) { red[wv] = s; red[4 + wv] = sq; }
  __syncthreads();
  if (t == 0) {
    const float S = red[0] + red[1] + red[2] + red[3];
    const float Q = red[4] + red[5] + red[6] + red[7];
    const float mu = S * (1.0f / NOUT);
    const float var = Q * (1.0f / NOUT) - mu * mu;
    red[0] = mu;
    red[1] = rsqrtf(var + 1e-5f);
  }
  __syncthreads();
  const float mu = red[0], rs = red[1];
  const float aP = pa[0];
  const float4 g4 = reinterpret_cast<const float4*>(gamma)[t];
  const float4 b4 = reinterpret_cast<const float4*>(beta)[t];
  float o0 = (v.x - mu) * rs * g4.x + b4.x;
  float o1 = (v.y - mu) * rs * g4.y + b4.y;
  float o2 = (v.z - mu) * rs * g4.z + b4.z;
  float o3 = (v.w - mu) * rs * g4.w + b4.w;
  v.x = o0 >= 0.0f ? o0 : aP * o0;
  v.y = o1 >= 0.0f ? o1 : aP * o1;
  v.z = o2 >= 0.0f ? o2 : aP * o2;
  v.w = o3 >= 0.0f ? o3 : aP * o3;
  reinterpret_cast<float4*>(yr)[t] = v;
}

// ---------------------------------------------------------------------------
extern "C" void kernel_launch(void* const* d_in, const int* in_sizes, int n_in,
                              void* d_out, int out_size, void* d_ws, size_t ws_size,
                              hipStream_t stream) {
  const float* x     = (const float*)d_in[0];
  const float* bw    = (const float*)d_in[1];
  const float* sw    = (const float*)d_in[2];
  const float* grid  = (const float*)d_in[3];
  const float* gamma = (const float*)d_in[4];
  const float* beta  = (const float*)d_in[5];
  const float* pa    = (const float*)d_in[6];
  float* out = (float*)d_out;

  __hip_bfloat16* Abuf = (__hip_bfloat16*)d_ws;                 // 8192 x 9216 bf16
  __hip_bfloat16* Wbuf = Abuf + (size_t)NB * KTOT;              // 1024 x 9216 bf16
  float* P0 = (float*)(Wbuf + (size_t)NOUT * KTOT);             // 8192 x 1024 f32

  prep<<<4096 + 4608, 256, 0, stream>>>(x, grid, Abuf, bw, sw, Wbuf);
  gemm_8ph<<<(NB / 256) * (NOUT / 256) * 2, 512, 0, stream>>>(Abuf, Wbuf, P0, out);
  reduce_ln_prelu<<<NB, 256, 0, stream>>>(P0, out, gamma, beta, pa);
}

// Round 9
// 198.682 us; speedup vs baseline: 1.4802x; 1.0189x over previous
//
#include <hip/hip_runtime.h>
#include <hip/hip_bf16.h>

typedef __attribute__((ext_vector_type(8))) short bf16x8;   // 8 bf16 (4 VGPRs)
typedef __attribute__((ext_vector_type(4))) float f32x4;    // MFMA C/D

#define KTOT 9216   // 1024 (gelu part) + 1024*8 (spline bases part)
#define KHALF 4608  // split-K slice
#define NB   8192
#define NIN  1024
#define NOUT 1024

__device__ __forceinline__ void load_lds16(const void* g, void* l) {
  __builtin_amdgcn_global_load_lds(
      (const __attribute__((address_space(1))) void*)g,
      (__attribute__((address_space(3))) void*)l, 16, 0, 0);
}

// ---------------------------------------------------------------------------
// Kernel 1 (merged prep): blocks [0,4096) build A; blocks [4096,8704) pack W.
// ---------------------------------------------------------------------------
__global__ void prep(const float* __restrict__ x,
                     const float* __restrict__ grid,
                     __hip_bfloat16* __restrict__ A,
                     const float* __restrict__ bw,
                     const float* __restrict__ sw,
                     __hip_bfloat16* __restrict__ W) {
  if (blockIdx.x < 4096) {
    const int tid = blockIdx.x * blockDim.x + threadIdx.x;
    const int i  = tid & (NIN - 1);
    const int b0 = (tid >> 10) << 3;                       // 8 rows / thread

    float g[12];
#pragma unroll
    for (int j = 0; j < 12; ++j) g[j] = grid[j];

    float invdr1[10], invdd1[10], invdr2[9], invdd2[9], invdr3[8], invdd3[8];
#pragma unroll
    for (int j = 0; j < 10; ++j) {
      invdr1[j] = __builtin_amdgcn_rcpf(g[j + 1] - g[j]);
      invdd1[j] = __builtin_amdgcn_rcpf(g[j + 2] - g[j + 1]);
    }
#pragma unroll
    for (int j = 0; j < 9; ++j) {
      invdr2[j] = __builtin_amdgcn_rcpf(g[j + 2] - g[j]);
      invdd2[j] = __builtin_amdgcn_rcpf(g[j + 3] - g[j + 1]);
    }
#pragma unroll
    for (int j = 0; j < 8; ++j) {
      invdr3[j] = __builtin_amdgcn_rcpf(g[j + 3] - g[j]);
      invdd3[j] = __builtin_amdgcn_rcpf(g[j + 4] - g[j + 1]);
    }

    for (int bb = 0; bb < 8; ++bb) {
      const int b = b0 + bb;
      const float xv = x[(size_t)b * NIN + i];
      const float ge = 0.5f * xv * (1.0f + erff(xv * 0.70710678118654752f));
      __hip_bfloat16* Arow = A + (size_t)b * KTOT;
      Arow[i] = __float2bfloat16(ge);

      float bas[11];
#pragma unroll
      for (int j = 0; j < 11; ++j)
        bas[j] = (xv >= g[j] && xv < g[j + 1]) ? 1.0f : 0.0f;
#pragma unroll
      for (int j = 0; j < 10; ++j)
        bas[j] = (xv - g[j]) * invdr1[j] * bas[j] + (g[j + 2] - xv) * invdd1[j] * bas[j + 1];
#pragma unroll
      for (int j = 0; j < 9; ++j)
        bas[j] = (xv - g[j]) * invdr2[j] * bas[j] + (g[j + 3] - xv) * invdd2[j] * bas[j + 1];
#pragma unroll
      for (int j = 0; j < 8; ++j)
        bas[j] = (xv - g[j]) * invdr3[j] * bas[j] + (g[j + 4] - xv) * invdd3[j] * bas[j + 1];

      union { __hip_bfloat16 h[8]; uint4 v; } u;
#pragma unroll
      for (int k = 0; k < 8; ++k) u.h[k] = __float2bfloat16(bas[k]);
      *reinterpret_cast<uint4*>(Arow + NIN + i * 8) = u.v;
    }
  } else {
    const int idx = (blockIdx.x - 4096) * blockDim.x + threadIdx.x;
    const int o  = idx / 1152;
    const int c8 = (idx - o * 1152) * 8;
    const float* src = (c8 < 1024) ? (bw + (size_t)o * 1024 + c8)
                                   : (sw + (size_t)o * 8192 + (c8 - 1024));
    float4 f0 = reinterpret_cast<const float4*>(src)[0];
    float4 f1 = reinterpret_cast<const float4*>(src)[1];
    union { __hip_bfloat16 h[8]; uint4 v; } u;
    u.h[0] = __float2bfloat16(f0.x); u.h[1] = __float2bfloat16(f0.y);
    u.h[2] = __float2bfloat16(f0.z); u.h[3] = __float2bfloat16(f0.w);
    u.h[4] = __float2bfloat16(f1.x); u.h[5] = __float2bfloat16(f1.y);
    u.h[6] = __float2bfloat16(f1.z); u.h[7] = __float2bfloat16(f1.w);
    *reinterpret_cast<uint4*>(W + (size_t)o * KTOT + c8) = u.v;
  }
}

// ---------------------------------------------------------------------------
// Kernel 2: 8-phase GEMM, reads-cross-barrier schedule.
// 256x256 tile, BK=64, split-K=2, 8 waves (2M x 4N), per-wave 128x64.
// LDS 160 KB: A ring-2 (2x32 KB) + B ring-3 (3x32 KB), XOR-swizzled.
// Phase = {reads(phi); stage; [vmcnt]; barrier; lgkmcnt(0); sched_barrier;
//          setprio MFMA setprio}. Reads issue pre-barrier and drain after it.
// Stage schedule: P1->A0(T+1), P2->A1(T+1) (lead-1, buf^1);
//                 P3->B0(T+2), P4->B1(T+2) (lead-2, slot (T+2)%3).
// All stages target regions >=3 barriers dead. Publish audit (steady):
//   A0',B0' read P1(T+1): drained by vmcnt(6)@P4(T)  [12 outstanding -> 6]
//   B1'     read P2(T+1): drained same vmcnt (older)
//   A1'     read P3(T+1): drained by vmcnt(8)@P2(T+1) [10 outstanding -> 8]
// Tail: T70 {vm(8), vm(2)}, T71 {vm(0), -}.
// ---------------------------------------------------------------------------
__global__ __launch_bounds__(512, 2)
void gemm_8ph(const __hip_bfloat16* __restrict__ A,
              const __hip_bfloat16* __restrict__ Bw,
              float* __restrict__ P0,
              float* __restrict__ P1w) {
  extern __shared__ char smem[];   // 160 KB: A[2][2][64r], B[3][2][...]

  const int tid  = threadIdx.x;
  const int lane = tid & 63;
  const int wave = tid >> 6;
  const int wr = wave >> 2;          // 0..1 -> M half (128 rows)
  const int wc = wave & 3;           // 0..3 -> N quarter (64 cols)

  const int orig = blockIdx.x;                    // 256 blocks
  const int bid  = (orig & 7) * 32 + (orig >> 3); // bijective XCD chunking
  const int ks    = bid & 1;                      // K slice
  const int tileN = (bid >> 1) & 3;               // 4 N tiles
  const int tileM = bid >> 3;                     // 32 M tiles
  const size_t brow = (size_t)tileM * 256;
  const size_t bcol = (size_t)tileN * 256;
  const int kbeg = ks * KHALF;

  const __hip_bfloat16* Ab = A  + brow * KTOT;
  const __hip_bfloat16* Bb = Bw + bcol * KTOT;
  float* C = ks ? P1w : P0;

  // ---- staging (pre-swizzled global source, linear LDS dest) ----
  const int swsrc = ((tid & 7) ^ ((tid >> 3) & 7)) * 8;
  const __hip_bfloat16* srcA = Ab + (size_t)(tid >> 3) * KTOT + kbeg + swsrc;
  const __hip_bfloat16* srcB = Bb + (size_t)(tid >> 3) * KTOT + kbeg + swsrc;
  const int wdst = wave * 1024;

#define AHALF(buf, h) (smem + (buf) * 32768 + (h) * 16384)
#define BHALF(slot, h) (smem + 65536 + (slot) * 32768 + (h) * 16384)

  auto stageA = [&](int bufA, int h, int kt) {
    const __hip_bfloat16* g = srcA + (size_t)h * (128 * KTOT) + (size_t)kt * 64;
    char* d = AHALF(bufA, h) + wdst;
    load_lds16(g, d);
    load_lds16(g + (size_t)64 * KTOT, d + 8192);
  };
  auto stageB = [&](int slot, int h, int kt) {
    const __hip_bfloat16* g = srcB + (size_t)h * (128 * KTOT) + (size_t)kt * 64;
    char* d = BHALF(slot, h) + wdst;
    load_lds16(g, d);
    load_lds16(g + (size_t)64 * KTOT, d + 8192);
  };

  // ---- fragment read addressing (XOR term is a per-lane constant) ----
  const int fr = lane & 15;
  const int hi = lane >> 4;                      // 0..3 -> k-slot within 32
  const int sw = (fr & 7) << 4;
  const int ax0 = (hi * 16) ^ sw;                // kk=0 slot byte
  const int ax1 = (64 + hi * 16) ^ sw;           // kk=1 slot byte

  bf16x8 a[4][2], b[4][2];
  f32x4 acc[8][4] = {};

#define RD_A(CBA, MH) { \
    const char* Ah = AHALF(CBA, wr) + (MH) * 8192; \
    _Pragma("unroll") \
    for (int mi2 = 0; mi2 < 4; ++mi2) { \
      const char* p = Ah + (mi2 * 16 + fr) * 128; \
      a[mi2][0] = *(const bf16x8*)(p + ax0); \
      a[mi2][1] = *(const bf16x8*)(p + ax1); } }

#define RD_B(SB, NH) { \
    const char* Bh = BHALF(SB, wc >> 1) + ((wc & 1) * 64 + (NH) * 32) * 128; \
    _Pragma("unroll") \
    for (int ni2 = 0; ni2 < 2; ++ni2) { \
      const char* p = Bh + (ni2 * 16 + fr) * 128; \
      b[(NH) * 2 + ni2][0] = *(const bf16x8*)(p + ax0); \
      b[(NH) * 2 + ni2][1] = *(const bf16x8*)(p + ax1); } }

// barrier first, THEN drain this wave's ds_reads (reads cross the barrier).
// sched_barrier(0) fences MFMA from being hoisted above the lgkm wait (rule 18).
#define PH_SYNC() do { \
    asm volatile("" ::: "memory"); \
    __builtin_amdgcn_s_barrier(); \
    asm volatile("s_waitcnt lgkmcnt(0)" ::: "memory"); \
    __builtin_amdgcn_sched_barrier(0); } while (0)

#define QMFMA(MH, NH) do { \
    __builtin_amdgcn_s_setprio(1); \
    _Pragma("unroll") \
    for (int mi2 = 0; mi2 < 4; ++mi2) \
      _Pragma("unroll") \
      for (int ni2 = 0; ni2 < 2; ++ni2) \
        _Pragma("unroll") \
        for (int kk = 0; kk < 2; ++kk) \
          acc[(MH) * 4 + mi2][(NH) * 2 + ni2] = \
            __builtin_amdgcn_mfma_f32_16x16x32_bf16(a[mi2][kk], b[(NH) * 2 + ni2][kk], \
                                                    acc[(MH) * 4 + mi2][(NH) * 2 + ni2], 0, 0, 0); \
    __builtin_amdgcn_s_setprio(0); } while (0)

#define TILE(T, CBA, SB, SB2, STA, STB, VM2, VM4) do { \
    /* P1 */ \
    RD_A(CBA, 0); RD_B(SB, 0); \
    if (STA) stageA((CBA) ^ 1, 0, (T) + 1); \
    PH_SYNC(); QMFMA(0, 0); \
    /* P2 */ \
    RD_B(SB, 1); \
    if (STA) stageA((CBA) ^ 1, 1, (T) + 1); \
    asm volatile(VM2 ::: "memory"); \
    PH_SYNC(); QMFMA(0, 1); \
    /* P3 */ \
    RD_A(CBA, 1); \
    if (STB) stageB(SB2, 0, (T) + 2); \
    PH_SYNC(); QMFMA(1, 1); \
    /* P4 */ \
    if (STB) stageB(SB2, 1, (T) + 2); \
    asm volatile(VM4 ::: "memory"); \
    PH_SYNC(); QMFMA(1, 0); \
  } while (0)

  // prologue: [B0(0),B1(0),A0(0),A1(0),B0(1),B1(1)] (12 loads); vmcnt(6)
  // drains through A0(0) -> P1(0)'s reads safe after the barrier.
  stageB(0, 0, 0); stageB(0, 1, 0);
  stageA(0, 0, 0); stageA(0, 1, 0);
  stageB(1, 0, 1); stageB(1, 1, 1);
  asm volatile("s_waitcnt vmcnt(6)" ::: "memory");
  __builtin_amdgcn_s_barrier();
  asm volatile("" ::: "memory");

  // main: T = 0..65 (11 iters x 6 tiles, period lcm(2,3)=6), steady waits
  for (int it = 0; it < 11; ++it) {
    TILE(it * 6 + 0, 0, 0, 2, 1, 1, "s_waitcnt vmcnt(8)", "s_waitcnt vmcnt(6)");
    TILE(it * 6 + 1, 1, 1, 0, 1, 1, "s_waitcnt vmcnt(8)", "s_waitcnt vmcnt(6)");
    TILE(it * 6 + 2, 0, 2, 1, 1, 1, "s_waitcnt vmcnt(8)", "s_waitcnt vmcnt(6)");
    TILE(it * 6 + 3, 1, 0, 2, 1, 1, "s_waitcnt vmcnt(8)", "s_waitcnt vmcnt(6)");
    TILE(it * 6 + 4, 0, 1, 0, 1, 1, "s_waitcnt vmcnt(8)", "s_waitcnt vmcnt(6)");
    TILE(it * 6 + 5, 1, 2, 1, 1, 1, "s_waitcnt vmcnt(8)", "s_waitcnt vmcnt(6)");
  }
  // tail: T = 66..71
  TILE(66, 0, 0, 2, 1, 1, "s_waitcnt vmcnt(8)", "s_waitcnt vmcnt(6)");
  TILE(67, 1, 1, 0, 1, 1, "s_waitcnt vmcnt(8)", "s_waitcnt vmcnt(6)");
  TILE(68, 0, 2, 1, 1, 1, "s_waitcnt vmcnt(8)", "s_waitcnt vmcnt(6)");
  TILE(69, 1, 0, 2, 1, 1, "s_waitcnt vmcnt(8)", "s_waitcnt vmcnt(6)");
  TILE(70, 0, 1, 0, 1, 0, "s_waitcnt vmcnt(8)", "s_waitcnt vmcnt(2)");
  TILE(71, 1, 2, 1, 0, 0, "s_waitcnt vmcnt(0)", "s_nop 0");

#undef TILE
#undef QMFMA
#undef PH_SYNC
#undef RD_B
#undef RD_A
#undef BHALF
#undef AHALF

  // epilogue: C/D layout col = lane&15, row = (lane>>4)*4 + reg
  const int crow0 = (lane >> 4) * 4;
#pragma unroll
  for (int mi = 0; mi < 8; ++mi)
#pragma unroll
    for (int ni = 0; ni < 4; ++ni) {
      const size_t r0 = brow + wr * 128 + mi * 16 + crow0;
      const size_t cc = bcol + wc * 64 + ni * 16 + fr;
      float* cp = C + r0 * NOUT + cc;
#pragma unroll
      for (int r = 0; r < 4; ++r) cp[(size_t)r * NOUT] = acc[mi][ni][r];
    }
}

// ---------------------------------------------------------------------------
// Kernel 3: y = P0 + P1 (split-K reduce), rowwise LayerNorm + PReLU -> y.
// P1 aliases d_out. One block per row.
// ---------------------------------------------------------------------------
__global__ void reduce_ln_prelu(const float* __restrict__ P0,
                                float* __restrict__ y,
                                const float* __restrict__ gamma,
                                const float* __restrict__ beta,
                                const float* __restrict__ pa) {
  const int row = blockIdx.x;
  const int t = threadIdx.x;                 // 256 threads, 4 floats each
  const float* p0r = P0 + (size_t)row * NOUT;
  float* yr = y + (size_t)row * NOUT;

  float4 aa = reinterpret_cast<const float4*>(p0r)[t];
  float4 v = reinterpret_cast<const float4*>(yr)[t];
  v.x += aa.x; v.y += aa.y; v.z += aa.z; v.w += aa.w;

  float s  = v.x + v.y + v.z + v.w;
  float sq = v.x * v.x + v.y * v.y + v.z * v.z + v.w * v.w;
#pragma unroll
  for (int off = 32; off > 0; off >>= 1) {
    s  += __shfl_down(s, off);
    sq += __shfl_down(sq, off);
  }
  __shared__ float red[8];
  const int wv = t >> 6, lane = t & 63;
  if (lane == 0) { red[wv] = s; red[4 + wv] = sq; }
  __syncthreads();
  if (t == 0) {
    const float S = red[0] + red[1] + red[2] + red[3];
    const float Q = red[4] + red[5] + red[6] + red[7];
    const float mu = S * (1.0f / NOUT);
    const float var = Q * (1.0f / NOUT) - mu * mu;
    red[0] = mu;
    red[1] = rsqrtf(var + 1e-5f);
  }
  __syncthreads();
  const float mu = red[0], rs = red[1];
  const float aP = pa[0];
  const float4 g4 = reinterpret_cast<const float4*>(gamma)[t];
  const float4 b4 = reinterpret_cast<const float4*>(beta)[t];
  float o0 = (v.x - mu) * rs * g4.x + b4.x;
  float o1 = (v.y - mu) * rs * g4.y + b4.y;
  float o2 = (v.z - mu) * rs * g4.z + b4.z;
  float o3 = (v.w - mu) * rs * g4.w + b4.w;
  v.x = o0 >= 0.0f ? o0 : aP * o0;
  v.y = o1 >= 0.0f ? o1 : aP * o1;
  v.z = o2 >= 0.0f ? o2 : aP * o2;
  v.w = o3 >= 0.0f ? o3 : aP * o3;
  reinterpret_cast<float4*>(yr)[t] = v;
}

// ---------------------------------------------------------------------------
extern "C" void kernel_launch(void* const* d_in, const int* in_sizes, int n_in,
                              void* d_out, int out_size, void* d_ws, size_t ws_size,
                              hipStream_t stream) {
  const float* x     = (const float*)d_in[0];
  const float* bw    = (const float*)d_in[1];
  const float* sw    = (const float*)d_in[2];
  const float* grid  = (const float*)d_in[3];
  const float* gamma = (const float*)d_in[4];
  const float* beta  = (const float*)d_in[5];
  const float* pa    = (const float*)d_in[6];
  float* out = (float*)d_out;

  __hip_bfloat16* Abuf = (__hip_bfloat16*)d_ws;                 // 8192 x 9216 bf16
  __hip_bfloat16* Wbuf = Abuf + (size_t)NB * KTOT;              // 1024 x 9216 bf16
  float* P0 = (float*)(Wbuf + (size_t)NOUT * KTOT);             // 8192 x 1024 f32

  // allow 160 KB dynamic LDS for the GEMM (idempotent, capture-safe)
  hipFuncSetAttribute(reinterpret_cast<const void*>(gemm_8ph),
                      hipFuncAttributeMaxDynamicSharedMemorySize, 163840);

  prep<<<4096 + 4608, 256, 0, stream>>>(x, grid, Abuf, bw, sw, Wbuf);
  gemm_8ph<<<(NB / 256) * (NOUT / 256) * 2, 512, 163840, stream>>>(Abuf, Wbuf, P0, out);
  reduce_ln_prelu<<<NB, 256, 0, stream>>>(P0, out, gamma, beta, pa);
}